// Round 1
// baseline (5329.282 us; speedup 1.0000x reference)
//
#include <hip/hip_runtime.h>
#include <hip/hip_bf16.h>

// ---------------------------------------------------------------------------
// SoftBlobGIN: correctness-first f32 baseline.
// Pipeline:
//   h = x@inp_w+b
//   3x GINE layer: z = h + scatter_add(relu(h[src]+e_emb) -> dst)
//                  t1 = z@W1+b1 ; bnstats(t1) ; t2 = relu(bn(t1))@W2+b2
//                  bnstats(t2) ; h = relu(bn(t2))
//   assign = softmax(relu(h@bh1)@bh2 + gumbel)
//   per-graph pooling (sorted batch): gmean, num[G,K,H], den[G,K]
//   blobs = LN(relu((num/den)@bm_w+b)) ; bemb = max_k
//   out = relu(bn(concat(gmean,bemb)@clf1+b))@clf2+b
// ---------------------------------------------------------------------------

#define HH 128

__device__ __forceinline__ void atomAddF(float* p, float v) {
    unsafeAtomicAdd(p, v);   // HW global_atomic_add_f32, no CAS loop
}

// out[r][c] = sum_k act(in[r][k]) * W[k][c] + bias[c]; act = identity or
// relu(v*scale[k]+shift[k]) when scale != nullptr.
template <int KD>
__global__ void k_gemm(const float* __restrict__ in, const float* __restrict__ W,
                       const float* __restrict__ bias, const float* __restrict__ scale,
                       const float* __restrict__ shift, float* __restrict__ out, int Nrows) {
    __shared__ float s_in[16][KD];
    const int t = threadIdx.x;            // 256
    const int c = t & 127;
    const int rh = t >> 7;                // 0..1
    const int row0 = blockIdx.x * 16;

    for (int e = t; e < 16 * KD; e += 256) {
        int r = e / KD, k = e - r * KD;
        int gr = row0 + r;
        float v = (gr < Nrows) ? in[(size_t)gr * KD + k] : 0.f;
        if (scale) v = fmaxf(v * scale[k] + shift[k], 0.f);
        s_in[r][k] = v;
    }
    __syncthreads();

    float acc[8];
#pragma unroll
    for (int i = 0; i < 8; i++) acc[i] = 0.f;

    for (int k = 0; k < KD; k += 4) {
        float w0 = W[(k + 0) * HH + c];
        float w1 = W[(k + 1) * HH + c];
        float w2 = W[(k + 2) * HH + c];
        float w3 = W[(k + 3) * HH + c];
#pragma unroll
        for (int i = 0; i < 8; i++) {
            const float4 iv = *(const float4*)(&s_in[rh * 8 + i][k]);
            acc[i] = fmaf(iv.x, w0, acc[i]);
            acc[i] = fmaf(iv.y, w1, acc[i]);
            acc[i] = fmaf(iv.z, w2, acc[i]);
            acc[i] = fmaf(iv.w, w3, acc[i]);
        }
    }
    const float b = bias[c];
    const int r0 = row0 + rh * 8;
#pragma unroll
    for (int i = 0; i < 8; i++)
        if (r0 + i < Nrows) out[(size_t)(r0 + i) * HH + c] = acc[i] + b;
}

// scatter: z[dst] += relu(h[src] + e_emb), one thread per (edge, 4 channels)
__global__ void k_scatter(const float* __restrict__ h, const int* __restrict__ ei,
                          const float* __restrict__ ew, const float* __restrict__ eb,
                          float* __restrict__ z, int E) {
    int idx = blockIdx.x * 256 + threadIdx.x;
    int e = idx >> 5;
    if (e >= E) return;
    int c4 = (idx & 31) << 2;
    int src = ei[e];
    int dst = ei[E + e];
    const float4 hv = *(const float4*)(h + (size_t)src * HH + c4);
    float e0 = ew[c4 + 0] + eb[c4 + 0];
    float e1 = ew[c4 + 1] + eb[c4 + 1];
    float e2 = ew[c4 + 2] + eb[c4 + 2];
    float e3 = ew[c4 + 3] + eb[c4 + 3];
    float* zp = z + (size_t)dst * HH + c4;
    atomAddF(zp + 0, fmaxf(hv.x + e0, 0.f));
    atomAddF(zp + 1, fmaxf(hv.y + e1, 0.f));
    atomAddF(zp + 2, fmaxf(hv.z + e2, 0.f));
    atomAddF(zp + 3, fmaxf(hv.w + e3, 0.f));
}

// column-wise sum / sumsq partials -> atomics into stats[0:128]=sum, [128:256]=sumsq
__global__ void k_bnstats(const float* __restrict__ t, float* __restrict__ stats, int Nrows) {
    __shared__ float s1[256], s2[256];
    const int tid = threadIdx.x;
    const int c = tid & 127;
    const int half = tid >> 7;
    const int rpb = (Nrows + gridDim.x - 1) / gridDim.x;
    const int r0 = blockIdx.x * rpb;
    const int r1 = min(r0 + rpb, Nrows);
    float a = 0.f, q = 0.f;
    for (int r = r0 + half; r < r1; r += 2) {
        float v = t[(size_t)r * HH + c];
        a += v;
        q += v * v;
    }
    s1[tid] = a;
    s2[tid] = q;
    __syncthreads();
    if (half == 0) {
        atomAddF(&stats[c], s1[c] + s1[c + 128]);
        atomAddF(&stats[128 + c], s2[c] + s2[c + 128]);
    }
}

__global__ void k_bnfin(const float* __restrict__ stats, const float* __restrict__ g,
                        const float* __restrict__ b, float* __restrict__ scale,
                        float* __restrict__ shift, float invN) {
    int c = threadIdx.x;  // 128
    float m = stats[c] * invN;
    float var = stats[128 + c] * invN - m * m;
    float s = g[c] * rsqrtf(var + 1e-5f);
    scale[c] = s;
    shift[c] = b[c] - m * s;
}

__global__ void k_bnrelu(const float* __restrict__ t, const float* __restrict__ sc,
                         const float* __restrict__ sh, float* __restrict__ h, int total4) {
    int i = blockIdx.x * 256 + threadIdx.x;
    if (i >= total4) return;
    int c4 = (i & 31) << 2;
    float4 v = *(const float4*)(t + (size_t)i * 4);
    float4 o;
    o.x = fmaxf(v.x * sc[c4 + 0] + sh[c4 + 0], 0.f);
    o.y = fmaxf(v.y * sc[c4 + 1] + sh[c4 + 1], 0.f);
    o.z = fmaxf(v.z * sc[c4 + 2] + sh[c4 + 2], 0.f);
    o.w = fmaxf(v.w * sc[c4 + 3] + sh[c4 + 3], 0.f);
    *(float4*)(h + (size_t)i * 4) = o;
}

// per-node: assign = softmax(relu(h@bh1+b1)@bh2+b2 + gumbel)
__global__ void k_assign(const float* __restrict__ h, const float* __restrict__ gum,
                         const float* __restrict__ w1, const float* __restrict__ b1,
                         const float* __restrict__ w2, const float* __restrict__ b2,
                         float* __restrict__ assign) {
    int n = blockIdx.x;
    int t = threadIdx.x;  // 64
    __shared__ float hr[128];
    __shared__ float hid[64];
    __shared__ float lg[8];
    hr[t] = h[(size_t)n * HH + t];
    hr[t + 64] = h[(size_t)n * HH + 64 + t];
    __syncthreads();
    float acc = b1[t];
    for (int k = 0; k < 128; k++) acc = fmaf(hr[k], w1[k * 64 + t], acc);
    hid[t] = fmaxf(acc, 0.f);
    __syncthreads();
    if (t < 8) {
        float a = b2[t];
        for (int j = 0; j < 64; j++) a = fmaf(hid[j], w2[j * 8 + t], a);
        lg[t] = a + gum[(size_t)n * 8 + t];
    }
    __syncthreads();
    if (t < 8) {
        float m = lg[0];
        for (int j = 1; j < 8; j++) m = fmaxf(m, lg[j]);
        float s = 0.f;
        for (int j = 0; j < 8; j++) s += expf(lg[j] - m);
        assign[(size_t)n * 8 + t] = expf(lg[t] - m) / s;
    }
}

__device__ __forceinline__ int lowerb(const int* __restrict__ arr, int n, int val) {
    int lo = 0, hi = n;
    while (lo < hi) {
        int mid = (lo + hi) >> 1;
        if (arr[mid] < val) lo = mid + 1;
        else hi = mid;
    }
    return lo;
}

// per-graph pooling: gmean[G,H], num[G,K,H], den[G,K]
__global__ void k_pool(const float* __restrict__ h, const float* __restrict__ assign,
                       const int* __restrict__ batch, float* __restrict__ gmean,
                       float* __restrict__ num, float* __restrict__ den, int N) {
    const int g = blockIdx.x;
    const int t = threadIdx.x;  // 256
    const int k = t >> 5;       // 0..7
    const int c4 = (t & 31) << 2;
    const int start = lowerb(batch, N, g);
    const int end = lowerb(batch, N, g + 1);
    float4 an = {0.f, 0.f, 0.f, 0.f};
    float4 gm = {0.f, 0.f, 0.f, 0.f};
    float ad = 0.f;
    for (int n = start; n < end; n++) {
        float a = assign[(size_t)n * 8 + k];
        const float4 hv = *(const float4*)(h + (size_t)n * HH + c4);
        an.x = fmaf(a, hv.x, an.x);
        an.y = fmaf(a, hv.y, an.y);
        an.z = fmaf(a, hv.z, an.z);
        an.w = fmaf(a, hv.w, an.w);
        if (k == 0) { gm.x += hv.x; gm.y += hv.y; gm.z += hv.z; gm.w += hv.w; }
        ad += a;
    }
    *(float4*)(num + ((size_t)g * 8 + k) * HH + c4) = an;
    if ((t & 31) == 0) den[(size_t)g * 8 + k] = ad;
    if (k == 0) {
        float inv = 1.f / (float)(end - start);
        float4 o = {gm.x * inv, gm.y * inv, gm.z * inv, gm.w * inv};
        *(float4*)(gmean + (size_t)g * HH + c4) = o;
    }
}

// per (g,k): row = num/den; y = relu(row@bm_w+b); LN; write blobs_ln
__global__ void k_blob(const float* __restrict__ num, const float* __restrict__ den,
                       const float* __restrict__ w, const float* __restrict__ b,
                       const float* __restrict__ lg, const float* __restrict__ lb,
                       float* __restrict__ blobs) {
    const int gk = blockIdx.x;  // G*K
    const int c = threadIdx.x;  // 128
    __shared__ float srow[128];
    __shared__ float red[4];
    float d = den[gk] + 1e-8f;
    srow[c] = num[(size_t)gk * HH + c] / d;
    __syncthreads();
    float acc = b[c];
    for (int j = 0; j < 128; j++) acc = fmaf(srow[j], w[j * HH + c], acc);
    float y = fmaxf(acc, 0.f);
    float s = y, q = y * y;
    for (int off = 32; off > 0; off >>= 1) {
        s += __shfl_down(s, off);
        q += __shfl_down(q, off);
    }
    if ((c & 63) == 0) { red[(c >> 6) * 2] = s; red[(c >> 6) * 2 + 1] = q; }
    __syncthreads();
    float S = red[0] + red[2], Q = red[1] + red[3];
    float m = S * (1.f / 128.f);
    float var = Q * (1.f / 128.f) - m * m;
    blobs[(size_t)gk * HH + c] = (y - m) * rsqrtf(var + 1e-5f) * lg[c] + lb[c];
}

__global__ void k_blobmax(const float* __restrict__ blobs, float* __restrict__ bemb) {
    int g = blockIdx.x;
    int c = threadIdx.x;  // 128
    float m = blobs[((size_t)g * 8) * HH + c];
    for (int k = 1; k < 8; k++) m = fmaxf(m, blobs[((size_t)g * 8 + k) * HH + c]);
    bemb[(size_t)g * HH + c] = m;
}

__global__ void k_clf1(const float* __restrict__ gmean, const float* __restrict__ bemb,
                       const float* __restrict__ w, const float* __restrict__ bias,
                       float* __restrict__ t4) {
    int g = blockIdx.x;
    int c = threadIdx.x;  // 128
    __shared__ float s[256];
    s[c] = gmean[(size_t)g * HH + c];
    s[128 + c] = bemb[(size_t)g * HH + c];
    __syncthreads();
    float acc = bias[c];
    for (int j = 0; j < 256; j++) acc = fmaf(s[j], w[j * HH + c], acc);
    t4[(size_t)g * HH + c] = acc;
}

__global__ void k_bnstats_small(const float* __restrict__ t4, const float* __restrict__ g,
                                const float* __restrict__ b, float* __restrict__ scale,
                                float* __restrict__ shift, int G) {
    int c = threadIdx.x;  // 128
    float a = 0.f, q = 0.f;
    for (int r = 0; r < G; r++) {
        float v = t4[(size_t)r * HH + c];
        a += v;
        q += v * v;
    }
    float invG = 1.f / (float)G;
    float m = a * invG;
    float var = q * invG - m * m;
    float s = g[c] * rsqrtf(var + 1e-5f);
    scale[c] = s;
    shift[c] = b[c] - m * s;
}

__global__ void k_clf2(const float* __restrict__ t4, const float* __restrict__ sc,
                       const float* __restrict__ sh, const float* __restrict__ w,
                       const float* __restrict__ bias, float* __restrict__ out) {
    int g = blockIdx.x;
    int t = threadIdx.x;  // 128
    __shared__ float s[128];
    s[t] = fmaxf(t4[(size_t)g * HH + t] * sc[t] + sh[t], 0.f);
    __syncthreads();
    if (t < 10) {
        float acc = bias[t];
        for (int j = 0; j < 128; j++) acc = fmaf(s[j], w[j * 10 + t], acc);
        out[(size_t)g * 10 + t] = acc;
    }
}

extern "C" void kernel_launch(void* const* d_in, const int* in_sizes, int n_in,
                              void* d_out, int out_size, void* d_ws, size_t ws_size,
                              hipStream_t stream) {
    const float* x      = (const float*)d_in[0];
    const int*   ei     = (const int*)d_in[1];
    const int*   batch  = (const int*)d_in[2];
    const float* gumbel = (const float*)d_in[3];
    const float* inp_w  = (const float*)d_in[4];
    const float* inp_b  = (const float*)d_in[5];
    const float* elin_w = (const float*)d_in[6];
    const float* elin_b = (const float*)d_in[7];
    const float* mlp1_w = (const float*)d_in[8];
    const float* mlp1_b = (const float*)d_in[9];
    const float* mlpbn_g = (const float*)d_in[10];
    const float* mlpbn_b = (const float*)d_in[11];
    const float* mlp2_w = (const float*)d_in[12];
    const float* mlp2_b = (const float*)d_in[13];
    const float* bn_g   = (const float*)d_in[14];
    const float* bn_b   = (const float*)d_in[15];
    const float* bh1_w  = (const float*)d_in[16];
    const float* bh1_b  = (const float*)d_in[17];
    const float* bh2_w  = (const float*)d_in[18];
    const float* bh2_b  = (const float*)d_in[19];
    const float* bm_w   = (const float*)d_in[20];
    const float* bm_b   = (const float*)d_in[21];
    const float* ln_g   = (const float*)d_in[22];
    const float* ln_b   = (const float*)d_in[23];
    const float* clf1_w = (const float*)d_in[24];
    const float* clf1_b = (const float*)d_in[25];
    const float* clfbn_g = (const float*)d_in[26];
    const float* clfbn_b = (const float*)d_in[27];
    const float* clf2_w = (const float*)d_in[28];
    const float* clf2_b = (const float*)d_in[29];
    float* out = (float*)d_out;

    const int N = in_sizes[0] / 64;
    const int E = in_sizes[1] / 2;
    const int G = out_size / 10;

    float* ws = (float*)d_ws;
    float* h      = ws;
    float* z      = ws + (size_t)N * HH;
    float* t1     = ws + (size_t)2 * N * HH;
    float* assign = ws + (size_t)3 * N * HH;
    float* gmean  = assign + (size_t)N * 8;
    float* num    = gmean + (size_t)G * HH;
    float* den    = num + (size_t)G * 8 * HH;
    float* blobs  = den + (size_t)G * 8;
    float* bemb   = blobs + (size_t)G * 8 * HH;
    float* t4     = bemb + (size_t)G * HH;
    float* stats  = t4 + (size_t)G * HH;   // 256 floats
    float* sc1    = stats + 256;
    float* sh1    = sc1 + 128;
    float* sc2    = sh1 + 128;
    float* sh2    = sc2 + 128;

    const dim3 B256(256), B128(128), B64(64);
    const int gemmGrid = (N + 15) / 16;
    const int scatGrid = (E * 32 + 255) / 256;
    const float invN = 1.f / (float)N;

    // h = x @ inp_w + inp_b
    k_gemm<64><<<gemmGrid, B256, 0, stream>>>(x, inp_w, inp_b, nullptr, nullptr, h, N);

    for (int l = 0; l < 3; l++) {
        // z = h; z += scatter(relu(h[src]+e_emb))
        hipMemcpyAsync(z, h, (size_t)N * HH * sizeof(float), hipMemcpyDeviceToDevice, stream);
        k_scatter<<<scatGrid, B256, 0, stream>>>(h, ei, elin_w + l * HH, elin_b + l * HH, z, E);
        // t1 = z @ W1 + b1
        k_gemm<128><<<gemmGrid, B256, 0, stream>>>(z, mlp1_w + (size_t)l * HH * HH,
                                                   mlp1_b + l * HH, nullptr, nullptr, t1, N);
        hipMemsetAsync(stats, 0, 256 * sizeof(float), stream);
        k_bnstats<<<512, B256, 0, stream>>>(t1, stats, N);
        k_bnfin<<<1, B128, 0, stream>>>(stats, mlpbn_g + l * HH, mlpbn_b + l * HH, sc1, sh1, invN);
        // t2 = relu(bn(t1)) @ W2 + b2  (into z)
        k_gemm<128><<<gemmGrid, B256, 0, stream>>>(t1, mlp2_w + (size_t)l * HH * HH,
                                                   mlp2_b + l * HH, sc1, sh1, z, N);
        hipMemsetAsync(stats, 0, 256 * sizeof(float), stream);
        k_bnstats<<<512, B256, 0, stream>>>(z, stats, N);
        k_bnfin<<<1, B128, 0, stream>>>(stats, bn_g + l * HH, bn_b + l * HH, sc2, sh2, invN);
        // h = relu(bn(z))
        k_bnrelu<<<(N * 32 + 255) / 256, B256, 0, stream>>>(z, sc2, sh2, h, N * 32);
    }

    k_assign<<<N, B64, 0, stream>>>(h, gumbel, bh1_w, bh1_b, bh2_w, bh2_b, assign);
    k_pool<<<G, B256, 0, stream>>>(h, assign, batch, gmean, num, den, N);
    k_blob<<<G * 8, B128, 0, stream>>>(num, den, bm_w, bm_b, ln_g, ln_b, blobs);
    k_blobmax<<<G, B128, 0, stream>>>(blobs, bemb);
    k_clf1<<<G, B128, 0, stream>>>(gmean, bemb, clf1_w, clf1_b, t4);
    k_bnstats_small<<<1, B128, 0, stream>>>(t4, clfbn_g, clfbn_b, sc1, sh1, G);
    k_clf2<<<G, B128, 0, stream>>>(t4, sc1, sh1, clf2_w, clf2_b, out);
}

// Round 2
// 1603.595 us; speedup vs baseline: 3.3233x; 3.3233x over previous
//
#include <hip/hip_runtime.h>
#include <hip/hip_bf16.h>

// ---------------------------------------------------------------------------
// SoftBlobGIN round 1: scatter-atomics -> CSR build + gather (no f32 atomics
// in the hot path). Everything else unchanged from the passing f32 baseline.
// ---------------------------------------------------------------------------

#define HH 128

__device__ __forceinline__ void atomAddF(float* p, float v) {
    unsafeAtomicAdd(p, v);
}

// ---------------- CSR build ----------------

__global__ void k_hist(const int* __restrict__ ei, int* __restrict__ deg, int E) {
    int e = blockIdx.x * 256 + threadIdx.x;
    if (e >= E) return;
    atomicAdd(&deg[ei[E + e]], 1);   // dst
}

// single-block exclusive scan of deg[0..N) -> rowptr[0..N], cursor copy
__global__ void k_scan(const int* __restrict__ deg, int* __restrict__ rowptr,
                       int* __restrict__ cursor, int N) {
    __shared__ int wsum[16];
    __shared__ int s_run;
    const int t = threadIdx.x;  // 1024
    const int lane = t & 63, w = t >> 6;
    if (t == 0) s_run = 0;
    __syncthreads();
    for (int base = 0; base < N; base += 1024) {
        int i = base + t;
        int v = (i < N) ? deg[i] : 0;
        int sv = v;  // inclusive scan within wave
        for (int off = 1; off < 64; off <<= 1) {
            int u = __shfl_up(sv, off);
            if (lane >= off) sv += u;
        }
        if (lane == 63) wsum[w] = sv;
        __syncthreads();
        if (w == 0 && lane < 16) {
            int ws_ = wsum[lane];
            for (int off = 1; off < 16; off <<= 1) {
                int u = __shfl_up(ws_, off);
                if (lane >= off) ws_ += u;
            }
            wsum[lane] = ws_;
        }
        __syncthreads();
        int waveoff = (w == 0) ? 0 : wsum[w - 1];
        int run = s_run;
        int excl = run + waveoff + (sv - v);
        if (i < N) { rowptr[i] = excl; cursor[i] = excl; }
        __syncthreads();
        if (t == 1023) s_run = run + wsum[15];
        __syncthreads();
    }
    if (t == 0) rowptr[N] = s_run;
}

__global__ void k_fill(const int* __restrict__ ei, int* __restrict__ cursor,
                       int* __restrict__ col, int E) {
    int e = blockIdx.x * 256 + threadIdx.x;
    if (e >= E) return;
    int src = ei[e];
    int dst = ei[E + e];
    int pos = atomicAdd(&cursor[dst], 1);
    col[pos] = src;
}

// z[n] = h[n] + sum_{e in in(n)} relu(h[src(e)] + e_emb); one wave per node
__global__ void k_gather(const float* __restrict__ h, const int* __restrict__ rowptr,
                         const int* __restrict__ col, const float* __restrict__ ew,
                         const float* __restrict__ eb, float* __restrict__ z, int N) {
    const int node = blockIdx.x * 4 + (threadIdx.x >> 6);
    if (node >= N) return;
    const int lane = threadIdx.x & 63;
    const int c2 = lane * 2;
    const float2 ee = {ew[c2] + eb[c2], ew[c2 + 1] + eb[c2 + 1]};
    float2 acc = {0.f, 0.f};
    const int s = rowptr[node], epend = rowptr[node + 1];
    int e = s;
    for (; e + 1 < epend; e += 2) {
        int s0 = col[e], s1 = col[e + 1];
        const float2 h0 = *(const float2*)(h + (size_t)s0 * HH + c2);
        const float2 h1 = *(const float2*)(h + (size_t)s1 * HH + c2);
        acc.x += fmaxf(h0.x + ee.x, 0.f);
        acc.y += fmaxf(h0.y + ee.y, 0.f);
        acc.x += fmaxf(h1.x + ee.x, 0.f);
        acc.y += fmaxf(h1.y + ee.y, 0.f);
    }
    if (e < epend) {
        int s0 = col[e];
        const float2 h0 = *(const float2*)(h + (size_t)s0 * HH + c2);
        acc.x += fmaxf(h0.x + ee.x, 0.f);
        acc.y += fmaxf(h0.y + ee.y, 0.f);
    }
    const float2 hn = *(const float2*)(h + (size_t)node * HH + c2);
    float2 o = {hn.x + acc.x, hn.y + acc.y};
    *(float2*)(z + (size_t)node * HH + c2) = o;
}

// ---------------- dense pipeline (unchanged) ----------------

template <int KD>
__global__ void k_gemm(const float* __restrict__ in, const float* __restrict__ W,
                       const float* __restrict__ bias, const float* __restrict__ scale,
                       const float* __restrict__ shift, float* __restrict__ out, int Nrows) {
    __shared__ float s_in[16][KD];
    const int t = threadIdx.x;            // 256
    const int c = t & 127;
    const int rh = t >> 7;                // 0..1
    const int row0 = blockIdx.x * 16;

    for (int e = t; e < 16 * KD; e += 256) {
        int r = e / KD, k = e - r * KD;
        int gr = row0 + r;
        float v = (gr < Nrows) ? in[(size_t)gr * KD + k] : 0.f;
        if (scale) v = fmaxf(v * scale[k] + shift[k], 0.f);
        s_in[r][k] = v;
    }
    __syncthreads();

    float acc[8];
#pragma unroll
    for (int i = 0; i < 8; i++) acc[i] = 0.f;

    for (int k = 0; k < KD; k += 4) {
        float w0 = W[(k + 0) * HH + c];
        float w1 = W[(k + 1) * HH + c];
        float w2 = W[(k + 2) * HH + c];
        float w3 = W[(k + 3) * HH + c];
#pragma unroll
        for (int i = 0; i < 8; i++) {
            const float4 iv = *(const float4*)(&s_in[rh * 8 + i][k]);
            acc[i] = fmaf(iv.x, w0, acc[i]);
            acc[i] = fmaf(iv.y, w1, acc[i]);
            acc[i] = fmaf(iv.z, w2, acc[i]);
            acc[i] = fmaf(iv.w, w3, acc[i]);
        }
    }
    const float b = bias[c];
    const int r0 = row0 + rh * 8;
#pragma unroll
    for (int i = 0; i < 8; i++)
        if (r0 + i < Nrows) out[(size_t)(r0 + i) * HH + c] = acc[i] + b;
}

__global__ void k_bnstats(const float* __restrict__ t, float* __restrict__ stats, int Nrows) {
    __shared__ float s1[256], s2[256];
    const int tid = threadIdx.x;
    const int c = tid & 127;
    const int half = tid >> 7;
    const int rpb = (Nrows + gridDim.x - 1) / gridDim.x;
    const int r0 = blockIdx.x * rpb;
    const int r1 = min(r0 + rpb, Nrows);
    float a = 0.f, q = 0.f;
    for (int r = r0 + half; r < r1; r += 2) {
        float v = t[(size_t)r * HH + c];
        a += v;
        q += v * v;
    }
    s1[tid] = a;
    s2[tid] = q;
    __syncthreads();
    if (half == 0) {
        atomAddF(&stats[c], s1[c] + s1[c + 128]);
        atomAddF(&stats[128 + c], s2[c] + s2[c + 128]);
    }
}

__global__ void k_bnfin(const float* __restrict__ stats, const float* __restrict__ g,
                        const float* __restrict__ b, float* __restrict__ scale,
                        float* __restrict__ shift, float invN) {
    int c = threadIdx.x;  // 128
    float m = stats[c] * invN;
    float var = stats[128 + c] * invN - m * m;
    float s = g[c] * rsqrtf(var + 1e-5f);
    scale[c] = s;
    shift[c] = b[c] - m * s;
}

__global__ void k_bnrelu(const float* __restrict__ t, const float* __restrict__ sc,
                         const float* __restrict__ sh, float* __restrict__ h, int total4) {
    int i = blockIdx.x * 256 + threadIdx.x;
    if (i >= total4) return;
    int c4 = (i & 31) << 2;
    float4 v = *(const float4*)(t + (size_t)i * 4);
    float4 o;
    o.x = fmaxf(v.x * sc[c4 + 0] + sh[c4 + 0], 0.f);
    o.y = fmaxf(v.y * sc[c4 + 1] + sh[c4 + 1], 0.f);
    o.z = fmaxf(v.z * sc[c4 + 2] + sh[c4 + 2], 0.f);
    o.w = fmaxf(v.w * sc[c4 + 3] + sh[c4 + 3], 0.f);
    *(float4*)(h + (size_t)i * 4) = o;
}

__global__ void k_assign(const float* __restrict__ h, const float* __restrict__ gum,
                         const float* __restrict__ w1, const float* __restrict__ b1,
                         const float* __restrict__ w2, const float* __restrict__ b2,
                         float* __restrict__ assign) {
    int n = blockIdx.x;
    int t = threadIdx.x;  // 64
    __shared__ float hr[128];
    __shared__ float hid[64];
    __shared__ float lg[8];
    hr[t] = h[(size_t)n * HH + t];
    hr[t + 64] = h[(size_t)n * HH + 64 + t];
    __syncthreads();
    float acc = b1[t];
    for (int k = 0; k < 128; k++) acc = fmaf(hr[k], w1[k * 64 + t], acc);
    hid[t] = fmaxf(acc, 0.f);
    __syncthreads();
    if (t < 8) {
        float a = b2[t];
        for (int j = 0; j < 64; j++) a = fmaf(hid[j], w2[j * 8 + t], a);
        lg[t] = a + gum[(size_t)n * 8 + t];
    }
    __syncthreads();
    if (t < 8) {
        float m = lg[0];
        for (int j = 1; j < 8; j++) m = fmaxf(m, lg[j]);
        float s = 0.f;
        for (int j = 0; j < 8; j++) s += expf(lg[j] - m);
        assign[(size_t)n * 8 + t] = expf(lg[t] - m) / s;
    }
}

__device__ __forceinline__ int lowerb(const int* __restrict__ arr, int n, int val) {
    int lo = 0, hi = n;
    while (lo < hi) {
        int mid = (lo + hi) >> 1;
        if (arr[mid] < val) lo = mid + 1;
        else hi = mid;
    }
    return lo;
}

__global__ void k_pool(const float* __restrict__ h, const float* __restrict__ assign,
                       const int* __restrict__ batch, float* __restrict__ gmean,
                       float* __restrict__ num, float* __restrict__ den, int N) {
    const int g = blockIdx.x;
    const int t = threadIdx.x;  // 256
    const int k = t >> 5;       // 0..7
    const int c4 = (t & 31) << 2;
    const int start = lowerb(batch, N, g);
    const int end = lowerb(batch, N, g + 1);
    float4 an = {0.f, 0.f, 0.f, 0.f};
    float4 gm = {0.f, 0.f, 0.f, 0.f};
    float ad = 0.f;
    for (int n = start; n < end; n++) {
        float a = assign[(size_t)n * 8 + k];
        const float4 hv = *(const float4*)(h + (size_t)n * HH + c4);
        an.x = fmaf(a, hv.x, an.x);
        an.y = fmaf(a, hv.y, an.y);
        an.z = fmaf(a, hv.z, an.z);
        an.w = fmaf(a, hv.w, an.w);
        if (k == 0) { gm.x += hv.x; gm.y += hv.y; gm.z += hv.z; gm.w += hv.w; }
        ad += a;
    }
    *(float4*)(num + ((size_t)g * 8 + k) * HH + c4) = an;
    if ((t & 31) == 0) den[(size_t)g * 8 + k] = ad;
    if (k == 0) {
        float inv = 1.f / (float)(end - start);
        float4 o = {gm.x * inv, gm.y * inv, gm.z * inv, gm.w * inv};
        *(float4*)(gmean + (size_t)g * HH + c4) = o;
    }
}

__global__ void k_blob(const float* __restrict__ num, const float* __restrict__ den,
                       const float* __restrict__ w, const float* __restrict__ b,
                       const float* __restrict__ lg, const float* __restrict__ lb,
                       float* __restrict__ blobs) {
    const int gk = blockIdx.x;  // G*K
    const int c = threadIdx.x;  // 128
    __shared__ float srow[128];
    __shared__ float red[4];
    float d = den[gk] + 1e-8f;
    srow[c] = num[(size_t)gk * HH + c] / d;
    __syncthreads();
    float acc = b[c];
    for (int j = 0; j < 128; j++) acc = fmaf(srow[j], w[j * HH + c], acc);
    float y = fmaxf(acc, 0.f);
    float s = y, q = y * y;
    for (int off = 32; off > 0; off >>= 1) {
        s += __shfl_down(s, off);
        q += __shfl_down(q, off);
    }
    if ((c & 63) == 0) { red[(c >> 6) * 2] = s; red[(c >> 6) * 2 + 1] = q; }
    __syncthreads();
    float S = red[0] + red[2], Q = red[1] + red[3];
    float m = S * (1.f / 128.f);
    float var = Q * (1.f / 128.f) - m * m;
    blobs[(size_t)gk * HH + c] = (y - m) * rsqrtf(var + 1e-5f) * lg[c] + lb[c];
}

__global__ void k_blobmax(const float* __restrict__ blobs, float* __restrict__ bemb) {
    int g = blockIdx.x;
    int c = threadIdx.x;  // 128
    float m = blobs[((size_t)g * 8) * HH + c];
    for (int k = 1; k < 8; k++) m = fmaxf(m, blobs[((size_t)g * 8 + k) * HH + c]);
    bemb[(size_t)g * HH + c] = m;
}

__global__ void k_clf1(const float* __restrict__ gmean, const float* __restrict__ bemb,
                       const float* __restrict__ w, const float* __restrict__ bias,
                       float* __restrict__ t4) {
    int g = blockIdx.x;
    int c = threadIdx.x;  // 128
    __shared__ float s[256];
    s[c] = gmean[(size_t)g * HH + c];
    s[128 + c] = bemb[(size_t)g * HH + c];
    __syncthreads();
    float acc = bias[c];
    for (int j = 0; j < 256; j++) acc = fmaf(s[j], w[j * HH + c], acc);
    t4[(size_t)g * HH + c] = acc;
}

__global__ void k_bnstats_small(const float* __restrict__ t4, const float* __restrict__ g,
                                const float* __restrict__ b, float* __restrict__ scale,
                                float* __restrict__ shift, int G) {
    int c = threadIdx.x;  // 128
    float a = 0.f, q = 0.f;
    for (int r = 0; r < G; r++) {
        float v = t4[(size_t)r * HH + c];
        a += v;
        q += v * v;
    }
    float invG = 1.f / (float)G;
    float m = a * invG;
    float var = q * invG - m * m;
    float s = g[c] * rsqrtf(var + 1e-5f);
    scale[c] = s;
    shift[c] = b[c] - m * s;
}

__global__ void k_clf2(const float* __restrict__ t4, const float* __restrict__ sc,
                       const float* __restrict__ sh, const float* __restrict__ w,
                       const float* __restrict__ bias, float* __restrict__ out) {
    int g = blockIdx.x;
    int t = threadIdx.x;  // 128
    __shared__ float s[128];
    s[t] = fmaxf(t4[(size_t)g * HH + t] * sc[t] + sh[t], 0.f);
    __syncthreads();
    if (t < 10) {
        float acc = bias[t];
        for (int j = 0; j < 128; j++) acc = fmaf(s[j], w[j * 10 + t], acc);
        out[(size_t)g * 10 + t] = acc;
    }
}

extern "C" void kernel_launch(void* const* d_in, const int* in_sizes, int n_in,
                              void* d_out, int out_size, void* d_ws, size_t ws_size,
                              hipStream_t stream) {
    const float* x      = (const float*)d_in[0];
    const int*   ei     = (const int*)d_in[1];
    const int*   batch  = (const int*)d_in[2];
    const float* gumbel = (const float*)d_in[3];
    const float* inp_w  = (const float*)d_in[4];
    const float* inp_b  = (const float*)d_in[5];
    const float* elin_w = (const float*)d_in[6];
    const float* elin_b = (const float*)d_in[7];
    const float* mlp1_w = (const float*)d_in[8];
    const float* mlp1_b = (const float*)d_in[9];
    const float* mlpbn_g = (const float*)d_in[10];
    const float* mlpbn_b = (const float*)d_in[11];
    const float* mlp2_w = (const float*)d_in[12];
    const float* mlp2_b = (const float*)d_in[13];
    const float* bn_g   = (const float*)d_in[14];
    const float* bn_b   = (const float*)d_in[15];
    const float* bh1_w  = (const float*)d_in[16];
    const float* bh1_b  = (const float*)d_in[17];
    const float* bh2_w  = (const float*)d_in[18];
    const float* bh2_b  = (const float*)d_in[19];
    const float* bm_w   = (const float*)d_in[20];
    const float* bm_b   = (const float*)d_in[21];
    const float* ln_g   = (const float*)d_in[22];
    const float* ln_b   = (const float*)d_in[23];
    const float* clf1_w = (const float*)d_in[24];
    const float* clf1_b = (const float*)d_in[25];
    const float* clfbn_g = (const float*)d_in[26];
    const float* clfbn_b = (const float*)d_in[27];
    const float* clf2_w = (const float*)d_in[28];
    const float* clf2_b = (const float*)d_in[29];
    float* out = (float*)d_out;

    const int N = in_sizes[0] / 64;
    const int E = in_sizes[1] / 2;
    const int G = out_size / 10;

    float* ws = (float*)d_ws;
    float* h      = ws;
    float* z      = ws + (size_t)N * HH;
    float* t1     = ws + (size_t)2 * N * HH;
    float* assign = ws + (size_t)3 * N * HH;
    float* gmean  = assign + (size_t)N * 8;
    float* num    = gmean + (size_t)G * HH;
    float* den    = num + (size_t)G * 8 * HH;
    float* blobs  = den + (size_t)G * 8;
    float* bemb   = blobs + (size_t)G * 8 * HH;
    float* t4     = bemb + (size_t)G * HH;
    float* stats  = t4 + (size_t)G * HH;   // 256 floats
    float* sc1    = stats + 256;
    float* sh1    = sc1 + 128;
    float* sc2    = sh1 + 128;
    float* sh2    = sc2 + 128;
    // CSR arrays (int) after the float region
    int* rowptr = (int*)(sh2 + 128);          // N+1
    int* cursor = rowptr + (N + 1);           // N
    int* colidx = cursor + N;                 // E

    const dim3 B256(256), B128(128), B64(64), B1024(1024);
    const int gemmGrid = (N + 15) / 16;
    const float invN = 1.f / (float)N;

    // ---- CSR build (deg reused in cursor slot first) ----
    hipMemsetAsync(cursor, 0, (size_t)N * sizeof(int), stream);
    k_hist<<<(E + 255) / 256, B256, 0, stream>>>(ei, cursor, E);
    k_scan<<<1, B1024, 0, stream>>>(cursor, rowptr, cursor, N);
    k_fill<<<(E + 255) / 256, B256, 0, stream>>>(ei, cursor, colidx, E);

    // h = x @ inp_w + inp_b
    k_gemm<64><<<gemmGrid, B256, 0, stream>>>(x, inp_w, inp_b, nullptr, nullptr, h, N);

    for (int l = 0; l < 3; l++) {
        // z = h + gather(relu(h[src]+e_emb))
        k_gather<<<(N + 3) / 4, B256, 0, stream>>>(h, rowptr, colidx,
                                                   elin_w + l * HH, elin_b + l * HH, z, N);
        // t1 = z @ W1 + b1
        k_gemm<128><<<gemmGrid, B256, 0, stream>>>(z, mlp1_w + (size_t)l * HH * HH,
                                                   mlp1_b + l * HH, nullptr, nullptr, t1, N);
        hipMemsetAsync(stats, 0, 256 * sizeof(float), stream);
        k_bnstats<<<512, B256, 0, stream>>>(t1, stats, N);
        k_bnfin<<<1, B128, 0, stream>>>(stats, mlpbn_g + l * HH, mlpbn_b + l * HH, sc1, sh1, invN);
        // t2 = relu(bn(t1)) @ W2 + b2  (into z)
        k_gemm<128><<<gemmGrid, B256, 0, stream>>>(t1, mlp2_w + (size_t)l * HH * HH,
                                                   mlp2_b + l * HH, sc1, sh1, z, N);
        hipMemsetAsync(stats, 0, 256 * sizeof(float), stream);
        k_bnstats<<<512, B256, 0, stream>>>(z, stats, N);
        k_bnfin<<<1, B128, 0, stream>>>(stats, bn_g + l * HH, bn_b + l * HH, sc2, sh2, invN);
        // h = relu(bn(z))
        k_bnrelu<<<(N * 32 + 255) / 256, B256, 0, stream>>>(z, sc2, sh2, h, N * 32);
    }

    k_assign<<<N, B64, 0, stream>>>(h, gumbel, bh1_w, bh1_b, bh2_w, bh2_b, assign);
    k_pool<<<G, B256, 0, stream>>>(h, assign, batch, gmean, num, den, N);
    k_blob<<<G * 8, B128, 0, stream>>>(num, den, bm_w, bm_b, ln_g, ln_b, blobs);
    k_blobmax<<<G, B128, 0, stream>>>(blobs, bemb);
    k_clf1<<<G, B128, 0, stream>>>(gmean, bemb, clf1_w, clf1_b, t4);
    k_bnstats_small<<<1, B128, 0, stream>>>(t4, clfbn_g, clfbn_b, sc1, sh1, G);
    k_clf2<<<G, B128, 0, stream>>>(t4, sc1, sh1, clf2_w, clf2_b, out);
}

// Round 4
// 836.125 us; speedup vs baseline: 6.3738x; 1.9179x over previous
//
#include <hip/hip_runtime.h>
#include <hip/hip_bf16.h>

// ---------------------------------------------------------------------------
// SoftBlobGIN round 4: split-precision bf16 MFMA GEMMs (hi+lo, 3 MFMAs/tile,
// ~f32 accuracy), all activations stored f32, fused BN stats/apply, LDS-staged
// assign kernel, CSR gather.
// ---------------------------------------------------------------------------

#define HH 128
typedef unsigned short u16;
typedef unsigned int u32;
typedef __attribute__((ext_vector_type(8))) short bf16x8;
typedef __attribute__((ext_vector_type(4))) float f32x4;

__device__ __forceinline__ void atomAddF(float* p, float v) { unsafeAtomicAdd(p, v); }

__device__ __forceinline__ u16 f2bf(float f) {          // RNE f32->bf16
    u32 u = __float_as_uint(f);
    u += 0x7fffu + ((u >> 16) & 1u);
    return (u16)(u >> 16);
}
__device__ __forceinline__ void split2(float v, u16& hi, u16& lo) {
    u16 h_ = f2bf(v);
    float hf = __uint_as_float(((u32)h_) << 16);
    hi = h_;
    lo = f2bf(v - hf);          // v - hf exact in f32; lo error ~2^-18 * |v|
}
// LDS XOR swizzle (G4/T2): breaks 16-way conflict of stride-256B b128 reads
__device__ __forceinline__ u32 swz(u32 row, u32 kByte, u32 strideB) {
    return (row * strideB + kByte) ^ ((row & 7u) << 4);
}

#define WTOT (8192 + 6 * 16384)

// ---------------- weight prep: f32 [K][128] -> bf16 hi/lo W^T [128][K] ------
__global__ void k_prep(const float* __restrict__ inp_w, const float* __restrict__ m1,
                       const float* __restrict__ m2, u16* __restrict__ Whi,
                       u16* __restrict__ Wlo) {
    int b = blockIdx.x;  // 0..6
    int t = threadIdx.x; // 256
    if (b == 0) {
        for (int idx = t; idx < 128 * 64; idx += 256) {
            int c = idx >> 6, k = idx & 63;
            u16 hi, lo;
            split2(inp_w[k * 128 + c], hi, lo);
            Whi[idx] = hi; Wlo[idx] = lo;
        }
    } else {
        const float* W = (b <= 3) ? m1 + (size_t)(b - 1) * 16384
                                  : m2 + (size_t)(b - 4) * 16384;
        u16* dh = Whi + 8192 + (size_t)(b - 1) * 16384;
        u16* dl = Wlo + 8192 + (size_t)(b - 1) * 16384;
        for (int idx = t; idx < 16384; idx += 256) {
            int c = idx >> 7, k = idx & 127;
            u16 hi, lo;
            split2(W[k * 128 + c], hi, lo);
            dh[idx] = hi; dl[idx] = lo;
        }
    }
}

// ---------------- CSR build ----------------
__global__ void k_hist(const int* __restrict__ ei, int* __restrict__ deg, int E) {
    int e = blockIdx.x * 256 + threadIdx.x;
    if (e >= E) return;
    atomicAdd(&deg[ei[E + e]], 1);
}

__global__ void k_bsum(const int* __restrict__ deg, int* __restrict__ bsum, int N) {
    int t = threadIdx.x;
    int i = blockIdx.x * 256 + t;
    int v = (i < N) ? deg[i] : 0;
    for (int o = 32; o; o >>= 1) v += __shfl_down(v, o);
    __shared__ int ws_[4];
    if ((t & 63) == 0) ws_[t >> 6] = v;
    __syncthreads();
    if (t == 0) bsum[blockIdx.x] = ws_[0] + ws_[1] + ws_[2] + ws_[3];
}

__global__ void k_scan1(const int* __restrict__ bsum, int* __restrict__ boff,
                        int* __restrict__ rowptrN, int nch) {
    int t = threadIdx.x;  // 256, nch <= 256
    int v = (t < nch) ? bsum[t] : 0;
    int l = t & 63, w = t >> 6;
    int sv = v;
    for (int o = 1; o < 64; o <<= 1) { int u = __shfl_up(sv, o); if (l >= o) sv += u; }
    __shared__ int wsum[4];
    if (l == 63) wsum[w] = sv;
    __syncthreads();
    int add = 0;
    for (int j = 0; j < w; j++) add += wsum[j];
    if (t < nch) boff[t] = sv - v + add;
    if (t == nch - 1) *rowptrN = sv + add;
}

__global__ void k_scan2(const int* __restrict__ deg, const int* __restrict__ boff,
                        int* __restrict__ rowptr, int* __restrict__ cursor, int N) {
    int b = blockIdx.x, t = threadIdx.x, i = b * 256 + t;
    int v = (i < N) ? deg[i] : 0;
    int l = t & 63, w = t >> 6;
    int sv = v;
    for (int o = 1; o < 64; o <<= 1) { int u = __shfl_up(sv, o); if (l >= o) sv += u; }
    __shared__ int wsum[4];
    if (l == 63) wsum[w] = sv;
    __syncthreads();
    int add = boff[b];
    for (int j = 0; j < w; j++) add += wsum[j];
    if (i < N) { int e = sv - v + add; rowptr[i] = e; cursor[i] = e; }
}

__global__ void k_fill(const int* __restrict__ ei, int* __restrict__ cursor,
                       int* __restrict__ col, int E) {
    int e = blockIdx.x * 256 + threadIdx.x;
    if (e >= E) return;
    int src = ei[e];
    int dst = ei[E + e];
    int pos = atomicAdd(&cursor[dst], 1);
    col[pos] = src;
}

// ---------------- split-precision MFMA GEMM: [N,KD]f32 @ [KD,128] + bias ----
// MODE 0: plain input | 1: input = relu(in*scale+shift)
// STATS: column sum/sumsq of (acc+bias) -> atomics into stats[256]
template <int KD, int MODE, bool STATS>
__global__ __launch_bounds__(256) void k_mgemm(
    const float* __restrict__ in, const u16* __restrict__ Whi,
    const u16* __restrict__ Wlo, const float* __restrict__ bias,
    const float* __restrict__ scale, const float* __restrict__ shift,
    float* __restrict__ out, float* __restrict__ stats, int Nrows) {
    __shared__ u16 s_Ahi[64 * KD];
    __shared__ u16 s_Alo[64 * KD];
    __shared__ u16 s_Bhi[128 * KD];
    __shared__ u16 s_Blo[128 * KD];
    __shared__ float s_red[2][4][128];
    const int t = threadIdx.x;
    const int brow0 = blockIdx.x * 64;
    constexpr u32 STR = KD * 2;

    // ---- stage A (f32 -> hi/lo bf16) ----
    {
        constexpr int KC = KD / 4;
#pragma unroll
        for (int i = 0; i < (64 * KC) / 256; i++) {
            int idx = i * 256 + t;
            int r = idx / KC, kc = idx % KC;
            int gr = brow0 + r;
            float4 v = {0.f, 0.f, 0.f, 0.f};
            if (gr < Nrows) v = *(const float4*)(in + (size_t)gr * KD + kc * 4);
            if (MODE == 1) {
                float4 sc = *(const float4*)(scale + kc * 4);
                float4 sh = *(const float4*)(shift + kc * 4);
                v.x = fmaxf(v.x * sc.x + sh.x, 0.f);
                v.y = fmaxf(v.y * sc.y + sh.y, 0.f);
                v.z = fmaxf(v.z * sc.z + sh.z, 0.f);
                v.w = fmaxf(v.w * sc.w + sh.w, 0.f);
            }
            u16 h0, h1, h2, h3, l0, l1, l2, l3;
            split2(v.x, h0, l0); split2(v.y, h1, l1);
            split2(v.z, h2, l2); split2(v.w, h3, l3);
            uint2 ph = {(u32)h0 | ((u32)h1 << 16), (u32)h2 | ((u32)h3 << 16)};
            uint2 pl = {(u32)l0 | ((u32)l1 << 16), (u32)l2 | ((u32)l3 << 16)};
            u32 off = swz(r, kc * 8, STR);
            *(uint2*)((char*)s_Ahi + off) = ph;
            *(uint2*)((char*)s_Alo + off) = pl;
        }
    }
    // ---- stage B (precomputed hi/lo W^T, linear [128][KD]) ----
    {
        constexpr int KCB = KD / 8;
#pragma unroll
        for (int i = 0; i < (128 * KCB) / 256; i++) {
            int idx = i * 256 + t;
            int c = idx / KCB, kc = idx % KCB;
            u32 off = swz(c, kc * 16, STR);
            *(uint4*)((char*)s_Bhi + off) = *(const uint4*)(Whi + (size_t)c * KD + kc * 8);
            *(uint4*)((char*)s_Blo + off) = *(const uint4*)(Wlo + (size_t)c * KD + kc * 8);
        }
    }
    __syncthreads();

    const int l = t & 63, w = t >> 6;
    const int c0 = l & 15;
    const u32 kOffB = (u32)(l >> 4) * 16u;   // byte offset of lane's k-slice
    f32x4 acc[8];
#pragma unroll
    for (int n = 0; n < 8; n++) acc[n] = (f32x4){0.f, 0.f, 0.f, 0.f};
    const u32 rA = w * 16 + c0;
#pragma unroll
    for (int kk = 0; kk < KD / 32; kk++) {
        u32 kb = kk * 64 + kOffB;
        bf16x8 ah = *(const bf16x8*)((char*)s_Ahi + swz(rA, kb, STR));
        bf16x8 al = *(const bf16x8*)((char*)s_Alo + swz(rA, kb, STR));
#pragma unroll
        for (int n = 0; n < 8; n++) {
            u32 ob = swz(n * 16 + c0, kb, STR);
            bf16x8 bh = *(const bf16x8*)((char*)s_Bhi + ob);
            bf16x8 bl = *(const bf16x8*)((char*)s_Blo + ob);
            acc[n] = __builtin_amdgcn_mfma_f32_16x16x32_bf16(ah, bh, acc[n], 0, 0, 0);
            acc[n] = __builtin_amdgcn_mfma_f32_16x16x32_bf16(al, bh, acc[n], 0, 0, 0);
            acc[n] = __builtin_amdgcn_mfma_f32_16x16x32_bf16(ah, bl, acc[n], 0, 0, 0);
        }
    }
    // ---- epilogue: bias, f32 store, fused bn-stats ----
    const int rbase = brow0 + w * 16 + ((l >> 4) << 2);
    float sN[8], qN[8];
#pragma unroll
    for (int n = 0; n < 8; n++) {
        const int colc = n * 16 + c0;
        const float bv = bias[colc];
        float s = 0.f, q = 0.f;
#pragma unroll
        for (int j = 0; j < 4; j++) {
            int gr = rbase + j;
            if (gr < Nrows) {
                float v = acc[n][j] + bv;
                out[(size_t)gr * HH + colc] = v;
                s += v;
                q += v * v;
            }
        }
        sN[n] = s;
        qN[n] = q;
    }
    if (STATS) {
#pragma unroll
        for (int n = 0; n < 8; n++) {
            sN[n] += __shfl_xor(sN[n], 16); sN[n] += __shfl_xor(sN[n], 32);
            qN[n] += __shfl_xor(qN[n], 16); qN[n] += __shfl_xor(qN[n], 32);
        }
        if (l < 16) {
#pragma unroll
            for (int n = 0; n < 8; n++) {
                s_red[0][w][n * 16 + l] = sN[n];
                s_red[1][w][n * 16 + l] = qN[n];
            }
        }
        __syncthreads();
        if (t < 128) {
            float S = s_red[0][0][t] + s_red[0][1][t] + s_red[0][2][t] + s_red[0][3][t];
            float Q = s_red[1][0][t] + s_red[1][1][t] + s_red[1][2][t] + s_red[1][3][t];
            atomAddF(&stats[t], S);
            atomAddF(&stats[HH + t], Q);
        }
    }
}

// ---------------- gather: z[n] = h[n] + sum relu(h[src]+ee)  (all f32) ------
__global__ void k_gather(const float* __restrict__ h, const int* __restrict__ rowptr,
                         const int* __restrict__ col, const float* __restrict__ ew,
                         const float* __restrict__ eb, float* __restrict__ z, int N) {
    const int node = blockIdx.x * 4 + (threadIdx.x >> 6);
    if (node >= N) return;
    const int lane = threadIdx.x & 63;
    const int c2 = lane * 2;
    const float2 ee = {ew[c2] + eb[c2], ew[c2 + 1] + eb[c2 + 1]};
    float2 acc = {0.f, 0.f};
    const int s = rowptr[node], epend = rowptr[node + 1];
    int e = s;
    for (; e + 1 < epend; e += 2) {
        int s0 = col[e], s1 = col[e + 1];
        const float2 h0 = *(const float2*)(h + (size_t)s0 * HH + c2);
        const float2 h1 = *(const float2*)(h + (size_t)s1 * HH + c2);
        acc.x += fmaxf(h0.x + ee.x, 0.f);
        acc.y += fmaxf(h0.y + ee.y, 0.f);
        acc.x += fmaxf(h1.x + ee.x, 0.f);
        acc.y += fmaxf(h1.y + ee.y, 0.f);
    }
    if (e < epend) {
        const float2 h0 = *(const float2*)(h + (size_t)col[e] * HH + c2);
        acc.x += fmaxf(h0.x + ee.x, 0.f);
        acc.y += fmaxf(h0.y + ee.y, 0.f);
    }
    const float2 hn = *(const float2*)(h + (size_t)node * HH + c2);
    float2 o = {hn.x + acc.x, hn.y + acc.y};
    *(float2*)(z + (size_t)node * HH + c2) = o;
}

// ---------------- BN finalize / apply ----------------
__global__ void k_bnfin(const float* __restrict__ stats, const float* __restrict__ g,
                        const float* __restrict__ b, float* __restrict__ scale,
                        float* __restrict__ shift, float invN) {
    int c = threadIdx.x;  // 128
    float m = stats[c] * invN;
    float var = stats[128 + c] * invN - m * m;
    float s = g[c] * rsqrtf(var + 1e-5f);
    scale[c] = s;
    shift[c] = b[c] - m * s;
}

__global__ void k_bnrelu(const float* __restrict__ t, const float* __restrict__ sc,
                         const float* __restrict__ sh, float* __restrict__ h, int total4) {
    int i = blockIdx.x * 256 + threadIdx.x;
    if (i >= total4) return;
    int c4 = (i & 31) << 2;
    float4 v = *(const float4*)(t + (size_t)i * 4);
    float4 o;
    o.x = fmaxf(v.x * sc[c4 + 0] + sh[c4 + 0], 0.f);
    o.y = fmaxf(v.y * sc[c4 + 1] + sh[c4 + 1], 0.f);
    o.z = fmaxf(v.z * sc[c4 + 2] + sh[c4 + 2], 0.f);
    o.w = fmaxf(v.w * sc[c4 + 3] + sh[c4 + 3], 0.f);
    *(float4*)(h + (size_t)i * 4) = o;
}

// ---------------- assign: 32 nodes/block, weights staged in LDS -------------
__global__ __launch_bounds__(256) void k_assign(
    const float* __restrict__ h, const float* __restrict__ gum,
    const float* __restrict__ w1, const float* __restrict__ b1,
    const float* __restrict__ w2, const float* __restrict__ b2,
    float* __restrict__ assign, int N) {
    __shared__ float s_w1[128 * 64];  // 32KB  w1[k][j]
    __shared__ float s_w2[64 * 8];    // 2KB   w2[j][kk]
    __shared__ float s_h[32][128];    // 16KB
    __shared__ float s_hid[32][64];   // 8KB
    const int t = threadIdx.x;
    const int n0 = blockIdx.x * 32;
    for (int i = t; i < 128 * 64; i += 256) s_w1[i] = w1[i];
    for (int i = t; i < 512; i += 256) s_w2[i] = w2[i];
    for (int i = t; i < 32 * 32; i += 256) {
        int r = i >> 5, c4 = (i & 31) << 2;
        int gn = n0 + r;
        float4 v = {0.f, 0.f, 0.f, 0.f};
        if (gn < N) v = *(const float4*)(h + (size_t)gn * HH + c4);
        *(float4*)(&s_h[r][c4]) = v;
    }
    __syncthreads();
    for (int o = t; o < 32 * 64; o += 256) {
        int nn = o >> 6, j = o & 63;
        float acc = b1[j];
        for (int k = 0; k < 128; k++) acc = fmaf(s_h[nn][k], s_w1[k * 64 + j], acc);
        s_hid[nn][j] = fmaxf(acc, 0.f);
    }
    __syncthreads();
    int nn = t >> 3, kk = t & 7;
    int gn = n0 + nn;
    float a = b2[kk];
    for (int j = 0; j < 64; j++) a = fmaf(s_hid[nn][j], s_w2[j * 8 + kk], a);
    if (gn < N) a += gum[(size_t)gn * 8 + kk];
    float m = a;
    m = fmaxf(m, __shfl_xor(m, 1));
    m = fmaxf(m, __shfl_xor(m, 2));
    m = fmaxf(m, __shfl_xor(m, 4));
    float e = expf(a - m);
    float s = e;
    s += __shfl_xor(s, 1); s += __shfl_xor(s, 2); s += __shfl_xor(s, 4);
    if (gn < N) assign[(size_t)gn * 8 + kk] = e / s;
}

// ---------------- tail ----------------
__device__ __forceinline__ int lowerb(const int* __restrict__ arr, int n, int val) {
    int lo = 0, hi = n;
    while (lo < hi) {
        int mid = (lo + hi) >> 1;
        if (arr[mid] < val) lo = mid + 1;
        else hi = mid;
    }
    return lo;
}

__global__ void k_pool(const float* __restrict__ h, const float* __restrict__ assign,
                       const int* __restrict__ batch, float* __restrict__ gmean,
                       float* __restrict__ num, float* __restrict__ den, int N) {
    const int g = blockIdx.x;
    const int t = threadIdx.x;  // 256
    const int k = t >> 5;
    const int c4 = (t & 31) << 2;
    const int start = lowerb(batch, N, g);
    const int end = lowerb(batch, N, g + 1);
    float4 an = {0.f, 0.f, 0.f, 0.f};
    float4 gm = {0.f, 0.f, 0.f, 0.f};
    float ad = 0.f;
    for (int n = start; n < end; n++) {
        float a = assign[(size_t)n * 8 + k];
        const float4 hv = *(const float4*)(h + (size_t)n * HH + c4);
        an.x = fmaf(a, hv.x, an.x);
        an.y = fmaf(a, hv.y, an.y);
        an.z = fmaf(a, hv.z, an.z);
        an.w = fmaf(a, hv.w, an.w);
        if (k == 0) { gm.x += hv.x; gm.y += hv.y; gm.z += hv.z; gm.w += hv.w; }
        ad += a;
    }
    *(float4*)(num + ((size_t)g * 8 + k) * HH + c4) = an;
    if ((t & 31) == 0) den[(size_t)g * 8 + k] = ad;
    if (k == 0) {
        float inv = 1.f / (float)(end - start);
        float4 o = {gm.x * inv, gm.y * inv, gm.z * inv, gm.w * inv};
        *(float4*)(gmean + (size_t)g * HH + c4) = o;
    }
}

__global__ void k_blob(const float* __restrict__ num, const float* __restrict__ den,
                       const float* __restrict__ w, const float* __restrict__ b,
                       const float* __restrict__ lg, const float* __restrict__ lb,
                       float* __restrict__ blobs) {
    const int gk = blockIdx.x;
    const int c = threadIdx.x;  // 128
    __shared__ float srow[128];
    __shared__ float red[4];
    float d = den[gk] + 1e-8f;
    srow[c] = num[(size_t)gk * HH + c] / d;
    __syncthreads();
    float acc = b[c];
    for (int j = 0; j < 128; j++) acc = fmaf(srow[j], w[j * HH + c], acc);
    float y = fmaxf(acc, 0.f);
    float s = y, q = y * y;
    for (int off = 32; off > 0; off >>= 1) {
        s += __shfl_down(s, off);
        q += __shfl_down(q, off);
    }
    if ((c & 63) == 0) { red[(c >> 6) * 2] = s; red[(c >> 6) * 2 + 1] = q; }
    __syncthreads();
    float S = red[0] + red[2], Q = red[1] + red[3];
    float m = S * (1.f / 128.f);
    float var = Q * (1.f / 128.f) - m * m;
    blobs[(size_t)gk * HH + c] = (y - m) * rsqrtf(var + 1e-5f) * lg[c] + lb[c];
}

__global__ void k_blobmax(const float* __restrict__ blobs, float* __restrict__ bemb) {
    int g = blockIdx.x;
    int c = threadIdx.x;  // 128
    float m = blobs[((size_t)g * 8) * HH + c];
    for (int k = 1; k < 8; k++) m = fmaxf(m, blobs[((size_t)g * 8 + k) * HH + c]);
    bemb[(size_t)g * HH + c] = m;
}

__global__ void k_clf1(const float* __restrict__ gmean, const float* __restrict__ bemb,
                       const float* __restrict__ w, const float* __restrict__ bias,
                       float* __restrict__ t4) {
    int g = blockIdx.x;
    int c = threadIdx.x;  // 128
    __shared__ float s[256];
    s[c] = gmean[(size_t)g * HH + c];
    s[128 + c] = bemb[(size_t)g * HH + c];
    __syncthreads();
    float acc = bias[c];
    for (int j = 0; j < 256; j++) acc = fmaf(s[j], w[j * HH + c], acc);
    t4[(size_t)g * HH + c] = acc;
}

__global__ void k_bnstats_small(const float* __restrict__ t4, const float* __restrict__ g,
                                const float* __restrict__ b, float* __restrict__ scale,
                                float* __restrict__ shift, int G) {
    int c = threadIdx.x;  // 128
    float a = 0.f, q = 0.f;
    for (int r = 0; r < G; r++) {
        float v = t4[(size_t)r * HH + c];
        a += v;
        q += v * v;
    }
    float invG = 1.f / (float)G;
    float m = a * invG;
    float var = q * invG - m * m;
    float s = g[c] * rsqrtf(var + 1e-5f);
    scale[c] = s;
    shift[c] = b[c] - m * s;
}

__global__ void k_clf2(const float* __restrict__ t4, const float* __restrict__ sc,
                       const float* __restrict__ sh, const float* __restrict__ w,
                       const float* __restrict__ bias, float* __restrict__ out) {
    int g = blockIdx.x;
    int t = threadIdx.x;  // 128
    __shared__ float s[128];
    s[t] = fmaxf(t4[(size_t)g * HH + t] * sc[t] + sh[t], 0.f);
    __syncthreads();
    if (t < 10) {
        float acc = bias[t];
        for (int j = 0; j < 128; j++) acc = fmaf(s[j], w[j * 10 + t], acc);
        out[(size_t)g * 10 + t] = acc;
    }
}

extern "C" void kernel_launch(void* const* d_in, const int* in_sizes, int n_in,
                              void* d_out, int out_size, void* d_ws, size_t ws_size,
                              hipStream_t stream) {
    const float* x      = (const float*)d_in[0];
    const int*   ei     = (const int*)d_in[1];
    const int*   batch  = (const int*)d_in[2];
    const float* gumbel = (const float*)d_in[3];
    const float* inp_w  = (const float*)d_in[4];
    const float* inp_b  = (const float*)d_in[5];
    const float* elin_w = (const float*)d_in[6];
    const float* elin_b = (const float*)d_in[7];
    const float* mlp1_w = (const float*)d_in[8];
    const float* mlp1_b = (const float*)d_in[9];
    const float* mlpbn_g = (const float*)d_in[10];
    const float* mlpbn_b = (const float*)d_in[11];
    const float* mlp2_w = (const float*)d_in[12];
    const float* mlp2_b = (const float*)d_in[13];
    const float* bn_g   = (const float*)d_in[14];
    const float* bn_b   = (const float*)d_in[15];
    const float* bh1_w  = (const float*)d_in[16];
    const float* bh1_b  = (const float*)d_in[17];
    const float* bh2_w  = (const float*)d_in[18];
    const float* bh2_b  = (const float*)d_in[19];
    const float* bm_w   = (const float*)d_in[20];
    const float* bm_b   = (const float*)d_in[21];
    const float* ln_g   = (const float*)d_in[22];
    const float* ln_b   = (const float*)d_in[23];
    const float* clf1_w = (const float*)d_in[24];
    const float* clf1_b = (const float*)d_in[25];
    const float* clfbn_g = (const float*)d_in[26];
    const float* clfbn_b = (const float*)d_in[27];
    const float* clf2_w = (const float*)d_in[28];
    const float* clf2_b = (const float*)d_in[29];
    float* out = (float*)d_out;

    const int N = in_sizes[0] / 64;
    const int E = in_sizes[1] / 2;
    const int G = out_size / 10;

    float* ws = (float*)d_ws;
    float* h      = ws;                                  // N*128
    float* z      = h + (size_t)N * HH;                  // N*128
    float* t1     = z + (size_t)N * HH;                  // N*128
    float* assign = t1 + (size_t)N * HH;                 // N*8
    float* gmean  = assign + (size_t)N * 8;              // G*128
    float* num    = gmean + (size_t)G * HH;              // G*8*128
    float* den    = num + (size_t)G * 8 * HH;            // G*8
    float* blobs  = den + (size_t)G * 8;                 // G*8*128
    float* bemb   = blobs + (size_t)G * 8 * HH;          // G*128
    float* t4     = bemb + (size_t)G * HH;               // G*128
    float* stats  = t4 + (size_t)G * HH;                 // 256
    float* sc1    = stats + 256;
    float* sh1    = sc1 + 128;
    float* sc2    = sh1 + 128;
    float* sh2    = sc2 + 128;
    u16* Whi = (u16*)(sh2 + 128);                        // WTOT
    u16* Wlo = Whi + WTOT;                               // WTOT
    int* rowptr = (int*)(Wlo + WTOT);                    // N+1
    int* cursor = rowptr + (N + 1);                      // N (also deg)
    int* colidx = cursor + N;                            // E
    int* bsum   = colidx + E;                            // 256
    int* boff   = bsum + 256;                            // 256

    const dim3 B256(256), B128(128);
    const int mg = (N + 63) / 64;
    const int nch = (N + 255) / 256;
    const float invN = 1.f / (float)N;

    // weight prep + CSR build
    k_prep<<<7, B256, 0, stream>>>(inp_w, mlp1_w, mlp2_w, Whi, Wlo);
    hipMemsetAsync(cursor, 0, (size_t)N * sizeof(int), stream);
    k_hist<<<(E + 255) / 256, B256, 0, stream>>>(ei, cursor, E);
    k_bsum<<<nch, B256, 0, stream>>>(cursor, bsum, N);
    k_scan1<<<1, B256, 0, stream>>>(bsum, boff, rowptr + N, nch);
    k_scan2<<<nch, B256, 0, stream>>>(cursor, boff, rowptr, cursor, N);
    k_fill<<<(E + 255) / 256, B256, 0, stream>>>(ei, cursor, colidx, E);

    // h = x @ inp_w + inp_b
    k_mgemm<64, 0, false><<<mg, B256, 0, stream>>>(
        x, Whi, Wlo, inp_b, nullptr, nullptr, h, nullptr, N);

    for (int l = 0; l < 3; l++) {
        k_gather<<<(N + 3) / 4, B256, 0, stream>>>(h, rowptr, colidx,
                                                   elin_w + l * HH, elin_b + l * HH, z, N);
        // t1 = z @ W1 + b1  (fused stats)
        hipMemsetAsync(stats, 0, 256 * sizeof(float), stream);
        k_mgemm<128, 0, true><<<mg, B256, 0, stream>>>(
            z, Whi + 8192 + (size_t)l * 16384, Wlo + 8192 + (size_t)l * 16384,
            mlp1_b + l * HH, nullptr, nullptr, t1, stats, N);
        k_bnfin<<<1, B128, 0, stream>>>(stats, mlpbn_g + l * HH, mlpbn_b + l * HH, sc1, sh1, invN);
        // t2 = relu(bn(t1)) @ W2 + b2 -> z  (fused bn-apply + stats)
        hipMemsetAsync(stats, 0, 256 * sizeof(float), stream);
        k_mgemm<128, 1, true><<<mg, B256, 0, stream>>>(
            t1, Whi + 8192 + (size_t)(3 + l) * 16384, Wlo + 8192 + (size_t)(3 + l) * 16384,
            mlp2_b + l * HH, sc1, sh1, z, stats, N);
        k_bnfin<<<1, B128, 0, stream>>>(stats, bn_g + l * HH, bn_b + l * HH, sc2, sh2, invN);
        // h = relu(bn(z))
        k_bnrelu<<<(N * 32 + 255) / 256, B256, 0, stream>>>(z, sc2, sh2, h, N * 32);
    }

    k_assign<<<(N + 31) / 32, B256, 0, stream>>>(h, gumbel, bh1_w, bh1_b, bh2_w, bh2_b, assign, N);
    k_pool<<<G, B256, 0, stream>>>(h, assign, batch, gmean, num, den, N);
    k_blob<<<G * 8, B128, 0, stream>>>(num, den, bm_w, bm_b, ln_g, ln_b, blobs);
    k_blobmax<<<G, B128, 0, stream>>>(blobs, bemb);
    k_clf1<<<G, B128, 0, stream>>>(gmean, bemb, clf1_w, clf1_b, t4);
    k_bnstats_small<<<1, B128, 0, stream>>>(t4, clfbn_g, clfbn_b, sc1, sh1, G);
    k_clf2<<<G, B128, 0, stream>>>(t4, sc1, sh1, clf2_w, clf2_b, out);
}

// Round 5
// 728.265 us; speedup vs baseline: 7.3178x; 1.1481x over previous
//
#include <hip/hip_runtime.h>
#include <hip/hip_bf16.h>

// ---------------------------------------------------------------------------
// SoftBlobGIN round 5: bf16 neighbor gather (f32 self/accum), persistent-B
// grid-stride split-precision MFMA GEMM with register A-prefetch.
// ---------------------------------------------------------------------------

#define HH 128
typedef unsigned short u16;
typedef unsigned int u32;
typedef __attribute__((ext_vector_type(8))) short bf16x8;
typedef __attribute__((ext_vector_type(4))) float f32x4;

__device__ __forceinline__ void atomAddF(float* p, float v) { unsafeAtomicAdd(p, v); }

__device__ __forceinline__ u16 f2bf(float f) {          // RNE f32->bf16
    u32 u = __float_as_uint(f);
    u += 0x7fffu + ((u >> 16) & 1u);
    return (u16)(u >> 16);
}
__device__ __forceinline__ float bf2f_lo(u32 u) { return __uint_as_float(u << 16); }
__device__ __forceinline__ float bf2f_hi(u32 u) { return __uint_as_float(u & 0xffff0000u); }
__device__ __forceinline__ void split2(float v, u16& hi, u16& lo) {
    u16 h_ = f2bf(v);
    float hf = __uint_as_float(((u32)h_) << 16);
    hi = h_;
    lo = f2bf(v - hf);
}
__device__ __forceinline__ u32 swz(u32 row, u32 kByte, u32 strideB) {
    return (row * strideB + kByte) ^ ((row & 7u) << 4);
}

#define WTOT (8192 + 6 * 16384)

// ---------------- weight prep ----------------
__global__ void k_prep(const float* __restrict__ inp_w, const float* __restrict__ m1,
                       const float* __restrict__ m2, u16* __restrict__ Whi,
                       u16* __restrict__ Wlo) {
    int b = blockIdx.x;  // 0..6
    int t = threadIdx.x; // 256
    if (b == 0) {
        for (int idx = t; idx < 128 * 64; idx += 256) {
            int c = idx >> 6, k = idx & 63;
            u16 hi, lo;
            split2(inp_w[k * 128 + c], hi, lo);
            Whi[idx] = hi; Wlo[idx] = lo;
        }
    } else {
        const float* W = (b <= 3) ? m1 + (size_t)(b - 1) * 16384
                                  : m2 + (size_t)(b - 4) * 16384;
        u16* dh = Whi + 8192 + (size_t)(b - 1) * 16384;
        u16* dl = Wlo + 8192 + (size_t)(b - 1) * 16384;
        for (int idx = t; idx < 16384; idx += 256) {
            int c = idx >> 7, k = idx & 127;
            u16 hi, lo;
            split2(W[k * 128 + c], hi, lo);
            dh[idx] = hi; dl[idx] = lo;
        }
    }
}

// ---------------- CSR build ----------------
__global__ void k_hist(const int* __restrict__ ei, int* __restrict__ deg, int E) {
    int e = blockIdx.x * 256 + threadIdx.x;
    if (e >= E) return;
    atomicAdd(&deg[ei[E + e]], 1);
}

__global__ void k_bsum(const int* __restrict__ deg, int* __restrict__ bsum, int N) {
    int t = threadIdx.x;
    int i = blockIdx.x * 256 + t;
    int v = (i < N) ? deg[i] : 0;
    for (int o = 32; o; o >>= 1) v += __shfl_down(v, o);
    __shared__ int ws_[4];
    if ((t & 63) == 0) ws_[t >> 6] = v;
    __syncthreads();
    if (t == 0) bsum[blockIdx.x] = ws_[0] + ws_[1] + ws_[2] + ws_[3];
}

__global__ void k_scan1(const int* __restrict__ bsum, int* __restrict__ boff,
                        int* __restrict__ rowptrN, int nch) {
    int t = threadIdx.x;  // 256
    int v = (t < nch) ? bsum[t] : 0;
    int l = t & 63, w = t >> 6;
    int sv = v;
    for (int o = 1; o < 64; o <<= 1) { int u = __shfl_up(sv, o); if (l >= o) sv += u; }
    __shared__ int wsum[4];
    if (l == 63) wsum[w] = sv;
    __syncthreads();
    int add = 0;
    for (int j = 0; j < w; j++) add += wsum[j];
    if (t < nch) boff[t] = sv - v + add;
    if (t == nch - 1) *rowptrN = sv + add;
}

__global__ void k_scan2(const int* __restrict__ deg, const int* __restrict__ boff,
                        int* __restrict__ rowptr, int* __restrict__ cursor, int N) {
    int b = blockIdx.x, t = threadIdx.x, i = b * 256 + t;
    int v = (i < N) ? deg[i] : 0;
    int l = t & 63, w = t >> 6;
    int sv = v;
    for (int o = 1; o < 64; o <<= 1) { int u = __shfl_up(sv, o); if (l >= o) sv += u; }
    __shared__ int wsum[4];
    if (l == 63) wsum[w] = sv;
    __syncthreads();
    int add = boff[b];
    for (int j = 0; j < w; j++) add += wsum[j];
    if (i < N) { int e = sv - v + add; rowptr[i] = e; cursor[i] = e; }
}

__global__ void k_fill(const int* __restrict__ ei, int* __restrict__ cursor,
                       int* __restrict__ col, int E) {
    int e = blockIdx.x * 256 + threadIdx.x;
    if (e >= E) return;
    int src = ei[e];
    int dst = ei[E + e];
    int pos = atomicAdd(&cursor[dst], 1);
    col[pos] = src;
}

// ---------------- persistent-B grid-stride split-precision MFMA GEMM --------
// MODE 0: plain input | 1: input = relu(in*scale+shift)
// STATS: column sum/sumsq of (acc+bias) -> atomics into stats[256]
// BOUT: also write bf16 copy of output
template <int KD, int MODE, bool STATS, bool BOUT>
__global__ __launch_bounds__(256) void k_mgemm(
    const float* __restrict__ in, const u16* __restrict__ Whi,
    const u16* __restrict__ Wlo, const float* __restrict__ bias,
    const float* __restrict__ scale, const float* __restrict__ shift,
    float* __restrict__ out, u16* __restrict__ outb,
    float* __restrict__ stats, int Nrows, int ntiles) {
    __shared__ u16 s_Ahi[64 * KD];
    __shared__ u16 s_Alo[64 * KD];
    __shared__ u16 s_Bhi[128 * KD];
    __shared__ u16 s_Blo[128 * KD];
    __shared__ float s_red[2][4][128];
    const int t = threadIdx.x;
    constexpr u32 STR = KD * 2;
    constexpr int KC = KD / 4;           // float4 chunks per row
    constexpr int NLD = (64 * KC) / 256; // per-thread float4 loads per tile

    // ---- stage B once ----
    {
        constexpr int KCB = KD / 8;
#pragma unroll
        for (int i = 0; i < (128 * KCB) / 256; i++) {
            int idx = i * 256 + t;
            int c = idx / KCB, kc = idx % KCB;
            u32 off = swz(c, kc * 16, STR);
            *(uint4*)((char*)s_Bhi + off) = *(const uint4*)(Whi + (size_t)c * KD + kc * 8);
            *(uint4*)((char*)s_Blo + off) = *(const uint4*)(Wlo + (size_t)c * KD + kc * 8);
        }
    }

    float4 rA[NLD];
    int tile = blockIdx.x;
    // prologue load of first tile
    if (tile < ntiles) {
#pragma unroll
        for (int i = 0; i < NLD; i++) {
            int idx = i * 256 + t;
            int r = idx / KC, kc = idx % KC;
            int gr = tile * 64 + r;
            rA[i] = (gr < Nrows) ? *(const float4*)(in + (size_t)gr * KD + kc * 4)
                                 : (float4){0.f, 0.f, 0.f, 0.f};
        }
    }

    const int l = t & 63, w = t >> 6;
    const int c0 = l & 15;
    const u32 kOffB = (u32)(l >> 4) * 16u;
    const u32 rA_row = w * 16 + c0;

    for (; tile < ntiles; tile += gridDim.x) {
        // ---- split regs -> LDS A ----
#pragma unroll
        for (int i = 0; i < NLD; i++) {
            int idx = i * 256 + t;
            int r = idx / KC, kc = idx % KC;
            float4 v = rA[i];
            if (MODE == 1) {
                float4 sc = *(const float4*)(scale + kc * 4);
                float4 sh = *(const float4*)(shift + kc * 4);
                v.x = fmaxf(v.x * sc.x + sh.x, 0.f);
                v.y = fmaxf(v.y * sc.y + sh.y, 0.f);
                v.z = fmaxf(v.z * sc.z + sh.z, 0.f);
                v.w = fmaxf(v.w * sc.w + sh.w, 0.f);
            }
            u16 h0, h1, h2, h3, l0, l1, l2, l3;
            split2(v.x, h0, l0); split2(v.y, h1, l1);
            split2(v.z, h2, l2); split2(v.w, h3, l3);
            uint2 ph = {(u32)h0 | ((u32)h1 << 16), (u32)h2 | ((u32)h3 << 16)};
            uint2 pl = {(u32)l0 | ((u32)l1 << 16), (u32)l2 | ((u32)l3 << 16)};
            u32 off = swz(r, kc * 8, STR);
            *(uint2*)((char*)s_Ahi + off) = ph;
            *(uint2*)((char*)s_Alo + off) = pl;
        }
        __syncthreads();  // A (and B on first iter) ready

        // ---- prefetch next tile into regs (latency hides under MFMA) ----
        int nxt = tile + gridDim.x;
        if (nxt < ntiles) {
#pragma unroll
            for (int i = 0; i < NLD; i++) {
                int idx = i * 256 + t;
                int r = idx / KC, kc = idx % KC;
                int gr = nxt * 64 + r;
                rA[i] = (gr < Nrows) ? *(const float4*)(in + (size_t)gr * KD + kc * 4)
                                     : (float4){0.f, 0.f, 0.f, 0.f};
            }
        }

        // ---- MFMA ----
        f32x4 acc[8];
#pragma unroll
        for (int n = 0; n < 8; n++) acc[n] = (f32x4){0.f, 0.f, 0.f, 0.f};
#pragma unroll
        for (int kk = 0; kk < KD / 32; kk++) {
            u32 kb = kk * 64 + kOffB;
            bf16x8 ah = *(const bf16x8*)((char*)s_Ahi + swz(rA_row, kb, STR));
            bf16x8 al = *(const bf16x8*)((char*)s_Alo + swz(rA_row, kb, STR));
#pragma unroll
            for (int n = 0; n < 8; n++) {
                u32 ob = swz(n * 16 + c0, kb, STR);
                bf16x8 bh = *(const bf16x8*)((char*)s_Bhi + ob);
                bf16x8 bl = *(const bf16x8*)((char*)s_Blo + ob);
                acc[n] = __builtin_amdgcn_mfma_f32_16x16x32_bf16(ah, bh, acc[n], 0, 0, 0);
                acc[n] = __builtin_amdgcn_mfma_f32_16x16x32_bf16(al, bh, acc[n], 0, 0, 0);
                acc[n] = __builtin_amdgcn_mfma_f32_16x16x32_bf16(ah, bl, acc[n], 0, 0, 0);
            }
        }

        // ---- epilogue ----
        const int rbase = tile * 64 + w * 16 + ((l >> 4) << 2);
#pragma unroll
        for (int n = 0; n < 8; n++) {
            const int colc = n * 16 + c0;
            const float bv = bias[colc];
            float s = 0.f, q = 0.f;
#pragma unroll
            for (int j = 0; j < 4; j++) {
                int gr = rbase + j;
                if (gr < Nrows) {
                    float v = acc[n][j] + bv;
                    out[(size_t)gr * HH + colc] = v;
                    if (BOUT) outb[(size_t)gr * HH + colc] = f2bf(v);
                    s += v;
                    q += v * v;
                }
            }
            if (STATS) {
                s += __shfl_xor(s, 16); s += __shfl_xor(s, 32);
                q += __shfl_xor(q, 16); q += __shfl_xor(q, 32);
                if (l < 16) {
                    s_red[0][w][n * 16 + l] = s;
                    s_red[1][w][n * 16 + l] = q;
                }
            }
        }
        __syncthreads();  // MFMA reads of s_A done; s_red complete
        if (STATS && t < 128) {
            float S = s_red[0][0][t] + s_red[0][1][t] + s_red[0][2][t] + s_red[0][3][t];
            float Q = s_red[1][0][t] + s_red[1][1][t] + s_red[1][2][t] + s_red[1][3][t];
            atomAddF(&stats[t], S);
            atomAddF(&stats[HH + t], Q);
        }
    }
}

// ---------------- gather: z[n] = h[n] + sum relu(bf16 h[src] + ee) ----------
__global__ void k_gather(const u16* __restrict__ hb, const float* __restrict__ h,
                         const int* __restrict__ rowptr, const int* __restrict__ col,
                         const float* __restrict__ ew, const float* __restrict__ eb,
                         float* __restrict__ z, int N) {
    const int node = blockIdx.x * 4 + (threadIdx.x >> 6);
    if (node >= N) return;
    const int lane = threadIdx.x & 63;
    const int c2 = lane * 2;
    const float2 ee = {ew[c2] + eb[c2], ew[c2 + 1] + eb[c2 + 1]};
    float2 acc = {0.f, 0.f};
    int e = rowptr[node];
    const int eend = rowptr[node + 1];
    for (; e + 1 < eend; e += 2) {
        int s0 = col[e], s1 = col[e + 1];
        u32 u0 = *(const u32*)(hb + (size_t)s0 * HH + c2);
        u32 u1 = *(const u32*)(hb + (size_t)s1 * HH + c2);
        acc.x += fmaxf(bf2f_lo(u0) + ee.x, 0.f);
        acc.y += fmaxf(bf2f_hi(u0) + ee.y, 0.f);
        acc.x += fmaxf(bf2f_lo(u1) + ee.x, 0.f);
        acc.y += fmaxf(bf2f_hi(u1) + ee.y, 0.f);
    }
    if (e < eend) {
        u32 u0 = *(const u32*)(hb + (size_t)col[e] * HH + c2);
        acc.x += fmaxf(bf2f_lo(u0) + ee.x, 0.f);
        acc.y += fmaxf(bf2f_hi(u0) + ee.y, 0.f);
    }
    const float2 hn = *(const float2*)(h + (size_t)node * HH + c2);
    float2 o = {hn.x + acc.x, hn.y + acc.y};
    *(float2*)(z + (size_t)node * HH + c2) = o;
}

// ---------------- BN finalize / apply ----------------
__global__ void k_bnfin(const float* __restrict__ stats, const float* __restrict__ g,
                        const float* __restrict__ b, float* __restrict__ scale,
                        float* __restrict__ shift, float invN) {
    int c = threadIdx.x;  // 128
    float m = stats[c] * invN;
    float var = stats[128 + c] * invN - m * m;
    float s = g[c] * rsqrtf(var + 1e-5f);
    scale[c] = s;
    shift[c] = b[c] - m * s;
}

// h = relu(bn(t)); writes f32 h and bf16 hb
__global__ void k_bnrelu(const float* __restrict__ t, const float* __restrict__ sc,
                         const float* __restrict__ sh, float* __restrict__ h,
                         u16* __restrict__ hb, int total4) {
    int i = blockIdx.x * 256 + threadIdx.x;
    if (i >= total4) return;
    int c4 = (i & 31) << 2;
    float4 v = *(const float4*)(t + (size_t)i * 4);
    float4 o;
    o.x = fmaxf(v.x * sc[c4 + 0] + sh[c4 + 0], 0.f);
    o.y = fmaxf(v.y * sc[c4 + 1] + sh[c4 + 1], 0.f);
    o.z = fmaxf(v.z * sc[c4 + 2] + sh[c4 + 2], 0.f);
    o.w = fmaxf(v.w * sc[c4 + 3] + sh[c4 + 3], 0.f);
    *(float4*)(h + (size_t)i * 4) = o;
    uint2 p = {(u32)f2bf(o.x) | ((u32)f2bf(o.y) << 16),
               (u32)f2bf(o.z) | ((u32)f2bf(o.w) << 16)};
    *(uint2*)(hb + (size_t)i * 4) = p;
}

// ---------------- assign: 32 nodes/block, weights staged in LDS -------------
__global__ __launch_bounds__(256) void k_assign(
    const float* __restrict__ h, const float* __restrict__ gum,
    const float* __restrict__ w1, const float* __restrict__ b1,
    const float* __restrict__ w2, const float* __restrict__ b2,
    float* __restrict__ assign, int N) {
    __shared__ float s_w1[128 * 64];
    __shared__ float s_w2[64 * 8];
    __shared__ float s_h[32][128];
    __shared__ float s_hid[32][64];
    const int t = threadIdx.x;
    const int n0 = blockIdx.x * 32;
    for (int i = t; i < 128 * 64; i += 256) s_w1[i] = w1[i];
    for (int i = t; i < 512; i += 256) s_w2[i] = w2[i];
    for (int i = t; i < 32 * 32; i += 256) {
        int r = i >> 5, c4 = (i & 31) << 2;
        int gn = n0 + r;
        float4 v = {0.f, 0.f, 0.f, 0.f};
        if (gn < N) v = *(const float4*)(h + (size_t)gn * HH + c4);
        *(float4*)(&s_h[r][c4]) = v;
    }
    __syncthreads();
    for (int o = t; o < 32 * 64; o += 256) {
        int nn = o >> 6, j = o & 63;
        float acc = b1[j];
        for (int k = 0; k < 128; k++) acc = fmaf(s_h[nn][k], s_w1[k * 64 + j], acc);
        s_hid[nn][j] = fmaxf(acc, 0.f);
    }
    __syncthreads();
    int nn = t >> 3, kk = t & 7;
    int gn = n0 + nn;
    float a = b2[kk];
    for (int j = 0; j < 64; j++) a = fmaf(s_hid[nn][j], s_w2[j * 8 + kk], a);
    if (gn < N) a += gum[(size_t)gn * 8 + kk];
    float m = a;
    m = fmaxf(m, __shfl_xor(m, 1));
    m = fmaxf(m, __shfl_xor(m, 2));
    m = fmaxf(m, __shfl_xor(m, 4));
    float e = expf(a - m);
    float s = e;
    s += __shfl_xor(s, 1); s += __shfl_xor(s, 2); s += __shfl_xor(s, 4);
    if (gn < N) assign[(size_t)gn * 8 + kk] = e / s;
}

// ---------------- tail ----------------
__device__ __forceinline__ int lowerb(const int* __restrict__ arr, int n, int val) {
    int lo = 0, hi = n;
    while (lo < hi) {
        int mid = (lo + hi) >> 1;
        if (arr[mid] < val) lo = mid + 1;
        else hi = mid;
    }
    return lo;
}

__global__ void k_pool(const float* __restrict__ h, const float* __restrict__ assign,
                       const int* __restrict__ batch, float* __restrict__ gmean,
                       float* __restrict__ num, float* __restrict__ den, int N) {
    const int g = blockIdx.x;
    const int t = threadIdx.x;  // 256
    const int k = t >> 5;
    const int c4 = (t & 31) << 2;
    const int start = lowerb(batch, N, g);
    const int end = lowerb(batch, N, g + 1);
    float4 an = {0.f, 0.f, 0.f, 0.f};
    float4 gm = {0.f, 0.f, 0.f, 0.f};
    float ad = 0.f;
    for (int n = start; n < end; n++) {
        float a = assign[(size_t)n * 8 + k];
        const float4 hv = *(const float4*)(h + (size_t)n * HH + c4);
        an.x = fmaf(a, hv.x, an.x);
        an.y = fmaf(a, hv.y, an.y);
        an.z = fmaf(a, hv.z, an.z);
        an.w = fmaf(a, hv.w, an.w);
        if (k == 0) { gm.x += hv.x; gm.y += hv.y; gm.z += hv.z; gm.w += hv.w; }
        ad += a;
    }
    *(float4*)(num + ((size_t)g * 8 + k) * HH + c4) = an;
    if ((t & 31) == 0) den[(size_t)g * 8 + k] = ad;
    if (k == 0) {
        float inv = 1.f / (float)(end - start);
        float4 o = {gm.x * inv, gm.y * inv, gm.z * inv, gm.w * inv};
        *(float4*)(gmean + (size_t)g * HH + c4) = o;
    }
}

__global__ void k_blob(const float* __restrict__ num, const float* __restrict__ den,
                       const float* __restrict__ w, const float* __restrict__ b,
                       const float* __restrict__ lg, const float* __restrict__ lb,
                       float* __restrict__ blobs) {
    const int gk = blockIdx.x;
    const int c = threadIdx.x;  // 128
    __shared__ float srow[128];
    __shared__ float red[4];
    float d = den[gk] + 1e-8f;
    srow[c] = num[(size_t)gk * HH + c] / d;
    __syncthreads();
    float acc = b[c];
    for (int j = 0; j < 128; j++) acc = fmaf(srow[j], w[j * HH + c], acc);
    float y = fmaxf(acc, 0.f);
    float s = y, q = y * y;
    for (int off = 32; off > 0; off >>= 1) {
        s += __shfl_down(s, off);
        q += __shfl_down(q, off);
    }
    if ((c & 63) == 0) { red[(c >> 6) * 2] = s; red[(c >> 6) * 2 + 1] = q; }
    __syncthreads();
    float S = red[0] + red[2], Q = red[1] + red[3];
    float m = S * (1.f / 128.f);
    float var = Q * (1.f / 128.f) - m * m;
    blobs[(size_t)gk * HH + c] = (y - m) * rsqrtf(var + 1e-5f) * lg[c] + lb[c];
}

__global__ void k_blobmax(const float* __restrict__ blobs, float* __restrict__ bemb) {
    int g = blockIdx.x;
    int c = threadIdx.x;  // 128
    float m = blobs[((size_t)g * 8) * HH + c];
    for (int k = 1; k < 8; k++) m = fmaxf(m, blobs[((size_t)g * 8 + k) * HH + c]);
    bemb[(size_t)g * HH + c] = m;
}

__global__ void k_clf1(const float* __restrict__ gmean, const float* __restrict__ bemb,
                       const float* __restrict__ w, const float* __restrict__ bias,
                       float* __restrict__ t4) {
    int g = blockIdx.x;
    int c = threadIdx.x;  // 128
    __shared__ float s[256];
    s[c] = gmean[(size_t)g * HH + c];
    s[128 + c] = bemb[(size_t)g * HH + c];
    __syncthreads();
    float acc = bias[c];
    for (int j = 0; j < 256; j++) acc = fmaf(s[j], w[j * HH + c], acc);
    t4[(size_t)g * HH + c] = acc;
}

__global__ void k_bnstats_small(const float* __restrict__ t4, const float* __restrict__ g,
                                const float* __restrict__ b, float* __restrict__ scale,
                                float* __restrict__ shift, int G) {
    int c = threadIdx.x;  // 128
    float a = 0.f, q = 0.f;
    for (int r = 0; r < G; r++) {
        float v = t4[(size_t)r * HH + c];
        a += v;
        q += v * v;
    }
    float invG = 1.f / (float)G;
    float m = a * invG;
    float var = q * invG - m * m;
    float s = g[c] * rsqrtf(var + 1e-5f);
    scale[c] = s;
    shift[c] = b[c] - m * s;
}

__global__ void k_clf2(const float* __restrict__ t4, const float* __restrict__ sc,
                       const float* __restrict__ sh, const float* __restrict__ w,
                       const float* __restrict__ bias, float* __restrict__ out) {
    int g = blockIdx.x;
    int t = threadIdx.x;  // 128
    __shared__ float s[128];
    s[t] = fmaxf(t4[(size_t)g * HH + t] * sc[t] + sh[t], 0.f);
    __syncthreads();
    if (t < 10) {
        float acc = bias[t];
        for (int j = 0; j < 128; j++) acc = fmaf(s[j], w[j * 10 + t], acc);
        out[(size_t)g * 10 + t] = acc;
    }
}

extern "C" void kernel_launch(void* const* d_in, const int* in_sizes, int n_in,
                              void* d_out, int out_size, void* d_ws, size_t ws_size,
                              hipStream_t stream) {
    const float* x      = (const float*)d_in[0];
    const int*   ei     = (const int*)d_in[1];
    const int*   batch  = (const int*)d_in[2];
    const float* gumbel = (const float*)d_in[3];
    const float* inp_w  = (const float*)d_in[4];
    const float* inp_b  = (const float*)d_in[5];
    const float* elin_w = (const float*)d_in[6];
    const float* elin_b = (const float*)d_in[7];
    const float* mlp1_w = (const float*)d_in[8];
    const float* mlp1_b = (const float*)d_in[9];
    const float* mlpbn_g = (const float*)d_in[10];
    const float* mlpbn_b = (const float*)d_in[11];
    const float* mlp2_w = (const float*)d_in[12];
    const float* mlp2_b = (const float*)d_in[13];
    const float* bn_g   = (const float*)d_in[14];
    const float* bn_b   = (const float*)d_in[15];
    const float* bh1_w  = (const float*)d_in[16];
    const float* bh1_b  = (const float*)d_in[17];
    const float* bh2_w  = (const float*)d_in[18];
    const float* bh2_b  = (const float*)d_in[19];
    const float* bm_w   = (const float*)d_in[20];
    const float* bm_b   = (const float*)d_in[21];
    const float* ln_g   = (const float*)d_in[22];
    const float* ln_b   = (const float*)d_in[23];
    const float* clf1_w = (const float*)d_in[24];
    const float* clf1_b = (const float*)d_in[25];
    const float* clfbn_g = (const float*)d_in[26];
    const float* clfbn_b = (const float*)d_in[27];
    const float* clf2_w = (const float*)d_in[28];
    const float* clf2_b = (const float*)d_in[29];
    float* out = (float*)d_out;

    const int N = in_sizes[0] / 64;
    const int E = in_sizes[1] / 2;
    const int G = out_size / 10;

    float* ws = (float*)d_ws;
    float* h      = ws;                                  // N*128
    float* z      = h + (size_t)N * HH;                  // N*128
    float* t1     = z + (size_t)N * HH;                  // N*128
    float* assign = t1 + (size_t)N * HH;                 // N*8
    float* gmean  = assign + (size_t)N * 8;              // G*128
    float* num    = gmean + (size_t)G * HH;              // G*8*128
    float* den    = num + (size_t)G * 8 * HH;            // G*8
    float* blobs  = den + (size_t)G * 8;                 // G*8*128
    float* bemb   = blobs + (size_t)G * 8 * HH;          // G*128
    float* t4     = bemb + (size_t)G * HH;               // G*128
    float* stats  = t4 + (size_t)G * HH;                 // 256
    float* sc1    = stats + 256;
    float* sh1    = sc1 + 128;
    float* sc2    = sh1 + 128;
    float* sh2    = sc2 + 128;
    u16* Whi = (u16*)(sh2 + 128);                        // WTOT
    u16* Wlo = Whi + WTOT;                               // WTOT
    int* rowptr = (int*)(Wlo + WTOT);                    // N+1
    int* cursor = rowptr + (N + 1);                      // N (also deg)
    int* colidx = cursor + N;                            // E
    int* bsum   = colidx + E;                            // 256
    int* boff   = bsum + 256;                            // 256
    // hb (bf16 h copy) aliases t1: hb live bnrelu(l)->gather(l+1), t1 live
    // mgemm1(l)->mgemm2(l), never simultaneously.
    u16* hb = (u16*)t1;

    const dim3 B256(256), B128(128);
    const int ntiles = (N + 63) / 64;
    const int gg = ntiles < 256 ? ntiles : 256;
    const int nch = (N + 255) / 256;
    const float invN = 1.f / (float)N;

    // weight prep + CSR build
    k_prep<<<7, B256, 0, stream>>>(inp_w, mlp1_w, mlp2_w, Whi, Wlo);
    hipMemsetAsync(cursor, 0, (size_t)N * sizeof(int), stream);
    k_hist<<<(E + 255) / 256, B256, 0, stream>>>(ei, cursor, E);
    k_bsum<<<nch, B256, 0, stream>>>(cursor, bsum, N);
    k_scan1<<<1, B256, 0, stream>>>(bsum, boff, rowptr + N, nch);
    k_scan2<<<nch, B256, 0, stream>>>(cursor, boff, rowptr, cursor, N);
    k_fill<<<(E + 255) / 256, B256, 0, stream>>>(ei, cursor, colidx, E);

    // h = x @ inp_w + inp_b  (f32 h + bf16 hb)
    k_mgemm<64, 0, false, true><<<gg, B256, 0, stream>>>(
        x, Whi, Wlo, inp_b, nullptr, nullptr, h, hb, nullptr, N, ntiles);

    for (int l = 0; l < 3; l++) {
        k_gather<<<(N + 3) / 4, B256, 0, stream>>>(hb, h, rowptr, colidx,
                                                   elin_w + l * HH, elin_b + l * HH, z, N);
        // t1 = z @ W1 + b1  (fused stats; overwrites hb region)
        hipMemsetAsync(stats, 0, 256 * sizeof(float), stream);
        k_mgemm<128, 0, true, false><<<gg, B256, 0, stream>>>(
            z, Whi + 8192 + (size_t)l * 16384, Wlo + 8192 + (size_t)l * 16384,
            mlp1_b + l * HH, nullptr, nullptr, t1, nullptr, stats, N, ntiles);
        k_bnfin<<<1, B128, 0, stream>>>(stats, mlpbn_g + l * HH, mlpbn_b + l * HH, sc1, sh1, invN);
        // t2 = relu(bn(t1)) @ W2 + b2 -> z  (fused bn-apply + stats)
        hipMemsetAsync(stats, 0, 256 * sizeof(float), stream);
        k_mgemm<128, 1, true, false><<<gg, B256, 0, stream>>>(
            t1, Whi + 8192 + (size_t)(3 + l) * 16384, Wlo + 8192 + (size_t)(3 + l) * 16384,
            mlp2_b + l * HH, sc1, sh1, z, nullptr, stats, N, ntiles);
        k_bnfin<<<1, B128, 0, stream>>>(stats, bn_g + l * HH, bn_b + l * HH, sc2, sh2, invN);
        // h = relu(bn(z)) -> f32 h + bf16 hb (hb overwrites dead t1)
        k_bnrelu<<<(N * 32 + 255) / 256, B256, 0, stream>>>(z, sc2, sh2, h, hb, N * 32);
    }

    k_assign<<<(N + 31) / 32, B256, 0, stream>>>(h, gumbel, bh1_w, bh1_b, bh2_w, bh2_b, assign, N);
    k_pool<<<G, B256, 0, stream>>>(h, assign, batch, gmean, num, den, N);
    k_blob<<<G * 8, B128, 0, stream>>>(num, den, bm_w, bm_b, ln_g, ln_b, blobs);
    k_blobmax<<<G, B128, 0, stream>>>(blobs, bemb);
    k_clf1<<<G, B128, 0, stream>>>(gmean, bemb, clf1_w, clf1_b, t4);
    k_bnstats_small<<<1, B128, 0, stream>>>(t4, clfbn_g, clfbn_b, sc1, sh1, G);
    k_clf2<<<G, B128, 0, stream>>>(t4, sc1, sh1, clf2_w, clf2_b, out);
}

// Round 6
// 623.117 us; speedup vs baseline: 8.5526x; 1.1687x over previous
//
#include <hip/hip_runtime.h>
#include <hip/hip_bf16.h>

// ---------------------------------------------------------------------------
// SoftBlobGIN round 6: parallel pool (1024 thr, 4 node strides), clf1 fused
// with blob-max + BN-stats atomics, bnfin self-clearing stats (1 memset).
// ---------------------------------------------------------------------------

#define HH 128
typedef unsigned short u16;
typedef unsigned int u32;
typedef __attribute__((ext_vector_type(8))) short bf16x8;
typedef __attribute__((ext_vector_type(4))) float f32x4;

__device__ __forceinline__ void atomAddF(float* p, float v) { unsafeAtomicAdd(p, v); }

__device__ __forceinline__ u16 f2bf(float f) {          // RNE f32->bf16
    u32 u = __float_as_uint(f);
    u += 0x7fffu + ((u >> 16) & 1u);
    return (u16)(u >> 16);
}
__device__ __forceinline__ float bf2f_lo(u32 u) { return __uint_as_float(u << 16); }
__device__ __forceinline__ float bf2f_hi(u32 u) { return __uint_as_float(u & 0xffff0000u); }
__device__ __forceinline__ void split2(float v, u16& hi, u16& lo) {
    u16 h_ = f2bf(v);
    float hf = __uint_as_float(((u32)h_) << 16);
    hi = h_;
    lo = f2bf(v - hf);
}
__device__ __forceinline__ u32 swz(u32 row, u32 kByte, u32 strideB) {
    return (row * strideB + kByte) ^ ((row & 7u) << 4);
}

#define WTOT (8192 + 6 * 16384)

// ---------------- weight prep ----------------
__global__ void k_prep(const float* __restrict__ inp_w, const float* __restrict__ m1,
                       const float* __restrict__ m2, u16* __restrict__ Whi,
                       u16* __restrict__ Wlo) {
    int b = blockIdx.x;  // 0..6
    int t = threadIdx.x; // 256
    if (b == 0) {
        for (int idx = t; idx < 128 * 64; idx += 256) {
            int c = idx >> 6, k = idx & 63;
            u16 hi, lo;
            split2(inp_w[k * 128 + c], hi, lo);
            Whi[idx] = hi; Wlo[idx] = lo;
        }
    } else {
        const float* W = (b <= 3) ? m1 + (size_t)(b - 1) * 16384
                                  : m2 + (size_t)(b - 4) * 16384;
        u16* dh = Whi + 8192 + (size_t)(b - 1) * 16384;
        u16* dl = Wlo + 8192 + (size_t)(b - 1) * 16384;
        for (int idx = t; idx < 16384; idx += 256) {
            int c = idx >> 7, k = idx & 127;
            u16 hi, lo;
            split2(W[k * 128 + c], hi, lo);
            dh[idx] = hi; dl[idx] = lo;
        }
    }
}

// ---------------- CSR build ----------------
__global__ void k_hist(const int* __restrict__ ei, int* __restrict__ deg, int E) {
    int e = blockIdx.x * 256 + threadIdx.x;
    if (e >= E) return;
    atomicAdd(&deg[ei[E + e]], 1);
}

__global__ void k_bsum(const int* __restrict__ deg, int* __restrict__ bsum, int N) {
    int t = threadIdx.x;
    int i = blockIdx.x * 256 + t;
    int v = (i < N) ? deg[i] : 0;
    for (int o = 32; o; o >>= 1) v += __shfl_down(v, o);
    __shared__ int ws_[4];
    if ((t & 63) == 0) ws_[t >> 6] = v;
    __syncthreads();
    if (t == 0) bsum[blockIdx.x] = ws_[0] + ws_[1] + ws_[2] + ws_[3];
}

__global__ void k_scan1(const int* __restrict__ bsum, int* __restrict__ boff,
                        int* __restrict__ rowptrN, int nch) {
    int t = threadIdx.x;  // 256
    int v = (t < nch) ? bsum[t] : 0;
    int l = t & 63, w = t >> 6;
    int sv = v;
    for (int o = 1; o < 64; o <<= 1) { int u = __shfl_up(sv, o); if (l >= o) sv += u; }
    __shared__ int wsum[4];
    if (l == 63) wsum[w] = sv;
    __syncthreads();
    int add = 0;
    for (int j = 0; j < w; j++) add += wsum[j];
    if (t < nch) boff[t] = sv - v + add;
    if (t == nch - 1) *rowptrN = sv + add;
}

__global__ void k_scan2(const int* __restrict__ deg, const int* __restrict__ boff,
                        int* __restrict__ rowptr, int* __restrict__ cursor, int N) {
    int b = blockIdx.x, t = threadIdx.x, i = b * 256 + t;
    int v = (i < N) ? deg[i] : 0;
    int l = t & 63, w = t >> 6;
    int sv = v;
    for (int o = 1; o < 64; o <<= 1) { int u = __shfl_up(sv, o); if (l >= o) sv += u; }
    __shared__ int wsum[4];
    if (l == 63) wsum[w] = sv;
    __syncthreads();
    int add = boff[b];
    for (int j = 0; j < w; j++) add += wsum[j];
    if (i < N) { int e = sv - v + add; rowptr[i] = e; cursor[i] = e; }
}

__global__ void k_fill(const int* __restrict__ ei, int* __restrict__ cursor,
                       int* __restrict__ col, int E) {
    int e = blockIdx.x * 256 + threadIdx.x;
    if (e >= E) return;
    int src = ei[e];
    int dst = ei[E + e];
    int pos = atomicAdd(&cursor[dst], 1);
    col[pos] = src;
}

// ---------------- persistent-B grid-stride split-precision MFMA GEMM --------
template <int KD, int MODE, bool STATS, bool BOUT>
__global__ __launch_bounds__(256) void k_mgemm(
    const float* __restrict__ in, const u16* __restrict__ Whi,
    const u16* __restrict__ Wlo, const float* __restrict__ bias,
    const float* __restrict__ scale, const float* __restrict__ shift,
    float* __restrict__ out, u16* __restrict__ outb,
    float* __restrict__ stats, int Nrows, int ntiles) {
    __shared__ u16 s_Ahi[64 * KD];
    __shared__ u16 s_Alo[64 * KD];
    __shared__ u16 s_Bhi[128 * KD];
    __shared__ u16 s_Blo[128 * KD];
    __shared__ float s_red[2][4][128];
    const int t = threadIdx.x;
    constexpr u32 STR = KD * 2;
    constexpr int KC = KD / 4;
    constexpr int NLD = (64 * KC) / 256;

    {
        constexpr int KCB = KD / 8;
#pragma unroll
        for (int i = 0; i < (128 * KCB) / 256; i++) {
            int idx = i * 256 + t;
            int c = idx / KCB, kc = idx % KCB;
            u32 off = swz(c, kc * 16, STR);
            *(uint4*)((char*)s_Bhi + off) = *(const uint4*)(Whi + (size_t)c * KD + kc * 8);
            *(uint4*)((char*)s_Blo + off) = *(const uint4*)(Wlo + (size_t)c * KD + kc * 8);
        }
    }

    float4 rA[NLD];
    int tile = blockIdx.x;
    if (tile < ntiles) {
#pragma unroll
        for (int i = 0; i < NLD; i++) {
            int idx = i * 256 + t;
            int r = idx / KC, kc = idx % KC;
            int gr = tile * 64 + r;
            rA[i] = (gr < Nrows) ? *(const float4*)(in + (size_t)gr * KD + kc * 4)
                                 : (float4){0.f, 0.f, 0.f, 0.f};
        }
    }

    const int l = t & 63, w = t >> 6;
    const int c0 = l & 15;
    const u32 kOffB = (u32)(l >> 4) * 16u;
    const u32 rA_row = w * 16 + c0;

    for (; tile < ntiles; tile += gridDim.x) {
#pragma unroll
        for (int i = 0; i < NLD; i++) {
            int idx = i * 256 + t;
            int r = idx / KC, kc = idx % KC;
            float4 v = rA[i];
            if (MODE == 1) {
                float4 sc = *(const float4*)(scale + kc * 4);
                float4 sh = *(const float4*)(shift + kc * 4);
                v.x = fmaxf(v.x * sc.x + sh.x, 0.f);
                v.y = fmaxf(v.y * sc.y + sh.y, 0.f);
                v.z = fmaxf(v.z * sc.z + sh.z, 0.f);
                v.w = fmaxf(v.w * sc.w + sh.w, 0.f);
            }
            u16 h0, h1, h2, h3, l0, l1, l2, l3;
            split2(v.x, h0, l0); split2(v.y, h1, l1);
            split2(v.z, h2, l2); split2(v.w, h3, l3);
            uint2 ph = {(u32)h0 | ((u32)h1 << 16), (u32)h2 | ((u32)h3 << 16)};
            uint2 pl = {(u32)l0 | ((u32)l1 << 16), (u32)l2 | ((u32)l3 << 16)};
            u32 off = swz(r, kc * 8, STR);
            *(uint2*)((char*)s_Ahi + off) = ph;
            *(uint2*)((char*)s_Alo + off) = pl;
        }
        __syncthreads();

        int nxt = tile + gridDim.x;
        if (nxt < ntiles) {
#pragma unroll
            for (int i = 0; i < NLD; i++) {
                int idx = i * 256 + t;
                int r = idx / KC, kc = idx % KC;
                int gr = nxt * 64 + r;
                rA[i] = (gr < Nrows) ? *(const float4*)(in + (size_t)gr * KD + kc * 4)
                                     : (float4){0.f, 0.f, 0.f, 0.f};
            }
        }

        f32x4 acc[8];
#pragma unroll
        for (int n = 0; n < 8; n++) acc[n] = (f32x4){0.f, 0.f, 0.f, 0.f};
#pragma unroll
        for (int kk = 0; kk < KD / 32; kk++) {
            u32 kb = kk * 64 + kOffB;
            bf16x8 ah = *(const bf16x8*)((char*)s_Ahi + swz(rA_row, kb, STR));
            bf16x8 al = *(const bf16x8*)((char*)s_Alo + swz(rA_row, kb, STR));
#pragma unroll
            for (int n = 0; n < 8; n++) {
                u32 ob = swz(n * 16 + c0, kb, STR);
                bf16x8 bh = *(const bf16x8*)((char*)s_Bhi + ob);
                bf16x8 bl = *(const bf16x8*)((char*)s_Blo + ob);
                acc[n] = __builtin_amdgcn_mfma_f32_16x16x32_bf16(ah, bh, acc[n], 0, 0, 0);
                acc[n] = __builtin_amdgcn_mfma_f32_16x16x32_bf16(al, bh, acc[n], 0, 0, 0);
                acc[n] = __builtin_amdgcn_mfma_f32_16x16x32_bf16(ah, bl, acc[n], 0, 0, 0);
            }
        }

        const int rbase = tile * 64 + w * 16 + ((l >> 4) << 2);
#pragma unroll
        for (int n = 0; n < 8; n++) {
            const int colc = n * 16 + c0;
            const float bv = bias[colc];
            float s = 0.f, q = 0.f;
#pragma unroll
            for (int j = 0; j < 4; j++) {
                int gr = rbase + j;
                if (gr < Nrows) {
                    float v = acc[n][j] + bv;
                    out[(size_t)gr * HH + colc] = v;
                    if (BOUT) outb[(size_t)gr * HH + colc] = f2bf(v);
                    s += v;
                    q += v * v;
                }
            }
            if (STATS) {
                s += __shfl_xor(s, 16); s += __shfl_xor(s, 32);
                q += __shfl_xor(q, 16); q += __shfl_xor(q, 32);
                if (l < 16) {
                    s_red[0][w][n * 16 + l] = s;
                    s_red[1][w][n * 16 + l] = q;
                }
            }
        }
        __syncthreads();
        if (STATS && t < 128) {
            float S = s_red[0][0][t] + s_red[0][1][t] + s_red[0][2][t] + s_red[0][3][t];
            float Q = s_red[1][0][t] + s_red[1][1][t] + s_red[1][2][t] + s_red[1][3][t];
            atomAddF(&stats[t], S);
            atomAddF(&stats[HH + t], Q);
        }
    }
}

// ---------------- gather: z[n] = h[n] + sum relu(bf16 h[src] + ee) ----------
__global__ void k_gather(const u16* __restrict__ hb, const float* __restrict__ h,
                         const int* __restrict__ rowptr, const int* __restrict__ col,
                         const float* __restrict__ ew, const float* __restrict__ eb,
                         float* __restrict__ z, int N) {
    const int node = blockIdx.x * 4 + (threadIdx.x >> 6);
    if (node >= N) return;
    const int lane = threadIdx.x & 63;
    const int c2 = lane * 2;
    const float2 ee = {ew[c2] + eb[c2], ew[c2 + 1] + eb[c2 + 1]};
    float2 acc = {0.f, 0.f};
    int e = rowptr[node];
    const int eend = rowptr[node + 1];
    for (; e + 1 < eend; e += 2) {
        int s0 = col[e], s1 = col[e + 1];
        u32 u0 = *(const u32*)(hb + (size_t)s0 * HH + c2);
        u32 u1 = *(const u32*)(hb + (size_t)s1 * HH + c2);
        acc.x += fmaxf(bf2f_lo(u0) + ee.x, 0.f);
        acc.y += fmaxf(bf2f_hi(u0) + ee.y, 0.f);
        acc.x += fmaxf(bf2f_lo(u1) + ee.x, 0.f);
        acc.y += fmaxf(bf2f_hi(u1) + ee.y, 0.f);
    }
    if (e < eend) {
        u32 u0 = *(const u32*)(hb + (size_t)col[e] * HH + c2);
        acc.x += fmaxf(bf2f_lo(u0) + ee.x, 0.f);
        acc.y += fmaxf(bf2f_hi(u0) + ee.y, 0.f);
    }
    const float2 hn = *(const float2*)(h + (size_t)node * HH + c2);
    float2 o = {hn.x + acc.x, hn.y + acc.y};
    *(float2*)(z + (size_t)node * HH + c2) = o;
}

// ---------------- BN finalize (self-clearing stats) ----------------
__global__ void k_bnfin(float* __restrict__ stats, const float* __restrict__ g,
                        const float* __restrict__ b, float* __restrict__ scale,
                        float* __restrict__ shift, float invN) {
    int c = threadIdx.x;  // 128
    float m = stats[c] * invN;
    float var = stats[128 + c] * invN - m * m;
    float s = g[c] * rsqrtf(var + 1e-5f);
    scale[c] = s;
    shift[c] = b[c] - m * s;
    stats[c] = 0.f;          // clear for next accumulation
    stats[128 + c] = 0.f;
}

// h = relu(bn(t)); writes f32 h and bf16 hb
__global__ void k_bnrelu(const float* __restrict__ t, const float* __restrict__ sc,
                         const float* __restrict__ sh, float* __restrict__ h,
                         u16* __restrict__ hb, int total4) {
    int i = blockIdx.x * 256 + threadIdx.x;
    if (i >= total4) return;
    int c4 = (i & 31) << 2;
    float4 v = *(const float4*)(t + (size_t)i * 4);
    float4 o;
    o.x = fmaxf(v.x * sc[c4 + 0] + sh[c4 + 0], 0.f);
    o.y = fmaxf(v.y * sc[c4 + 1] + sh[c4 + 1], 0.f);
    o.z = fmaxf(v.z * sc[c4 + 2] + sh[c4 + 2], 0.f);
    o.w = fmaxf(v.w * sc[c4 + 3] + sh[c4 + 3], 0.f);
    *(float4*)(h + (size_t)i * 4) = o;
    uint2 p = {(u32)f2bf(o.x) | ((u32)f2bf(o.y) << 16),
               (u32)f2bf(o.z) | ((u32)f2bf(o.w) << 16)};
    *(uint2*)(hb + (size_t)i * 4) = p;
}

// ---------------- assign ----------------
__global__ __launch_bounds__(256) void k_assign(
    const float* __restrict__ h, const float* __restrict__ gum,
    const float* __restrict__ w1, const float* __restrict__ b1,
    const float* __restrict__ w2, const float* __restrict__ b2,
    float* __restrict__ assign, int N) {
    __shared__ float s_w1[128 * 64];
    __shared__ float s_w2[64 * 8];
    __shared__ float s_h[32][128];
    __shared__ float s_hid[32][64];
    const int t = threadIdx.x;
    const int n0 = blockIdx.x * 32;
    for (int i = t; i < 128 * 64; i += 256) s_w1[i] = w1[i];
    for (int i = t; i < 512; i += 256) s_w2[i] = w2[i];
    for (int i = t; i < 32 * 32; i += 256) {
        int r = i >> 5, c4 = (i & 31) << 2;
        int gn = n0 + r;
        float4 v = {0.f, 0.f, 0.f, 0.f};
        if (gn < N) v = *(const float4*)(h + (size_t)gn * HH + c4);
        *(float4*)(&s_h[r][c4]) = v;
    }
    __syncthreads();
    for (int o = t; o < 32 * 64; o += 256) {
        int nn = o >> 6, j = o & 63;
        float acc = b1[j];
        for (int k = 0; k < 128; k++) acc = fmaf(s_h[nn][k], s_w1[k * 64 + j], acc);
        s_hid[nn][j] = fmaxf(acc, 0.f);
    }
    __syncthreads();
    int nn = t >> 3, kk = t & 7;
    int gn = n0 + nn;
    float a = b2[kk];
    for (int j = 0; j < 64; j++) a = fmaf(s_hid[nn][j], s_w2[j * 8 + kk], a);
    if (gn < N) a += gum[(size_t)gn * 8 + kk];
    float m = a;
    m = fmaxf(m, __shfl_xor(m, 1));
    m = fmaxf(m, __shfl_xor(m, 2));
    m = fmaxf(m, __shfl_xor(m, 4));
    float e = expf(a - m);
    float s = e;
    s += __shfl_xor(s, 1); s += __shfl_xor(s, 2); s += __shfl_xor(s, 4);
    if (gn < N) assign[(size_t)gn * 8 + kk] = e / s;
}

// ---------------- tail ----------------
__device__ __forceinline__ int lowerb(const int* __restrict__ arr, int n, int val) {
    int lo = 0, hi = n;
    while (lo < hi) {
        int mid = (lo + hi) >> 1;
        if (arr[mid] < val) lo = mid + 1;
        else hi = mid;
    }
    return lo;
}

// pool: 1024 threads = 4 node-strides x (8 k x 32 lanes); LDS combine
__global__ __launch_bounds__(1024) void k_pool(
    const float* __restrict__ h, const float* __restrict__ assign,
    const int* __restrict__ batch, float* __restrict__ gmean,
    float* __restrict__ num, float* __restrict__ den, int N) {
    __shared__ float4 s_num[4][8][32];  // 16KB
    __shared__ float4 s_gm[4][32];      // 2KB
    __shared__ float s_den[4][8];
    const int g = blockIdx.x;
    const int t = threadIdx.x;
    const int ns = t >> 8;
    const int k = (t >> 5) & 7;
    const int lane = t & 31;
    const int c4 = lane << 2;
    const int start = lowerb(batch, N, g);
    const int end = lowerb(batch, N, g + 1);
    float4 an = {0.f, 0.f, 0.f, 0.f};
    float4 gm = {0.f, 0.f, 0.f, 0.f};
    float ad = 0.f;
    for (int n = start + ns; n < end; n += 4) {
        float a = assign[(size_t)n * 8 + k];
        const float4 hv = *(const float4*)(h + (size_t)n * HH + c4);
        an.x = fmaf(a, hv.x, an.x);
        an.y = fmaf(a, hv.y, an.y);
        an.z = fmaf(a, hv.z, an.z);
        an.w = fmaf(a, hv.w, an.w);
        if (k == 0) { gm.x += hv.x; gm.y += hv.y; gm.z += hv.z; gm.w += hv.w; }
        ad += a;
    }
    s_num[ns][k][lane] = an;
    if (k == 0) s_gm[ns][lane] = gm;
    if (lane == 0) s_den[ns][k] = ad;
    __syncthreads();
    if (t < 256) {
        float4 a0 = s_num[0][k][lane], a1 = s_num[1][k][lane];
        float4 a2 = s_num[2][k][lane], a3 = s_num[3][k][lane];
        float4 o = {a0.x + a1.x + a2.x + a3.x, a0.y + a1.y + a2.y + a3.y,
                    a0.z + a1.z + a2.z + a3.z, a0.w + a1.w + a2.w + a3.w};
        *(float4*)(num + ((size_t)g * 8 + k) * HH + c4) = o;
        if (t < 32) {
            float4 g0 = s_gm[0][lane], g1 = s_gm[1][lane];
            float4 g2 = s_gm[2][lane], g3 = s_gm[3][lane];
            int cnt = end - start;
            float inv = 1.f / (float)(cnt > 0 ? cnt : 1);
            float4 om = {(g0.x + g1.x + g2.x + g3.x) * inv,
                         (g0.y + g1.y + g2.y + g3.y) * inv,
                         (g0.z + g1.z + g2.z + g3.z) * inv,
                         (g0.w + g1.w + g2.w + g3.w) * inv};
            *(float4*)(gmean + (size_t)g * HH + c4) = om;
        }
        if (t < 8) den[(size_t)g * 8 + t] =
            s_den[0][t] + s_den[1][t] + s_den[2][t] + s_den[3][t];
    }
}

__global__ void k_blob(const float* __restrict__ num, const float* __restrict__ den,
                       const float* __restrict__ w, const float* __restrict__ b,
                       const float* __restrict__ lg, const float* __restrict__ lb,
                       float* __restrict__ blobs) {
    const int gk = blockIdx.x;
    const int c = threadIdx.x;  // 128
    __shared__ float srow[128];
    __shared__ float red[4];
    float d = den[gk] + 1e-8f;
    srow[c] = num[(size_t)gk * HH + c] / d;
    __syncthreads();
    float acc = b[c];
    for (int j = 0; j < 128; j++) acc = fmaf(srow[j], w[j * HH + c], acc);
    float y = fmaxf(acc, 0.f);
    float s = y, q = y * y;
    for (int off = 32; off > 0; off >>= 1) {
        s += __shfl_down(s, off);
        q += __shfl_down(q, off);
    }
    if ((c & 63) == 0) { red[(c >> 6) * 2] = s; red[(c >> 6) * 2 + 1] = q; }
    __syncthreads();
    float S = red[0] + red[2], Q = red[1] + red[3];
    float m = S * (1.f / 128.f);
    float var = Q * (1.f / 128.f) - m * m;
    blobs[(size_t)gk * HH + c] = (y - m) * rsqrtf(var + 1e-5f) * lg[c] + lb[c];
}

// clf1: fused blob-max + gemm + BN-stats atomics
__global__ void k_clf1(const float* __restrict__ gmean, const float* __restrict__ blobs,
                       const float* __restrict__ w, const float* __restrict__ bias,
                       float* __restrict__ t4, float* __restrict__ stats) {
    int g = blockIdx.x;
    int c = threadIdx.x;  // 128
    __shared__ float s[256];
    float m = blobs[((size_t)g * 8) * HH + c];
#pragma unroll
    for (int k = 1; k < 8; k++) m = fmaxf(m, blobs[((size_t)g * 8 + k) * HH + c]);
    s[c] = gmean[(size_t)g * HH + c];
    s[128 + c] = m;
    __syncthreads();
    float acc = bias[c];
    for (int j = 0; j < 256; j++) acc = fmaf(s[j], w[j * HH + c], acc);
    t4[(size_t)g * HH + c] = acc;
    atomAddF(&stats[c], acc);
    atomAddF(&stats[HH + c], acc * acc);
}

__global__ void k_clf2(const float* __restrict__ t4, const float* __restrict__ sc,
                       const float* __restrict__ sh, const float* __restrict__ w,
                       const float* __restrict__ bias, float* __restrict__ out) {
    int g = blockIdx.x;
    int t = threadIdx.x;  // 128
    __shared__ float s[128];
    s[t] = fmaxf(t4[(size_t)g * HH + t] * sc[t] + sh[t], 0.f);
    __syncthreads();
    if (t < 10) {
        float acc = bias[t];
        for (int j = 0; j < 128; j++) acc = fmaf(s[j], w[j * 10 + t], acc);
        out[(size_t)g * 10 + t] = acc;
    }
}

extern "C" void kernel_launch(void* const* d_in, const int* in_sizes, int n_in,
                              void* d_out, int out_size, void* d_ws, size_t ws_size,
                              hipStream_t stream) {
    const float* x      = (const float*)d_in[0];
    const int*   ei     = (const int*)d_in[1];
    const int*   batch  = (const int*)d_in[2];
    const float* gumbel = (const float*)d_in[3];
    const float* inp_w  = (const float*)d_in[4];
    const float* inp_b  = (const float*)d_in[5];
    const float* elin_w = (const float*)d_in[6];
    const float* elin_b = (const float*)d_in[7];
    const float* mlp1_w = (const float*)d_in[8];
    const float* mlp1_b = (const float*)d_in[9];
    const float* mlpbn_g = (const float*)d_in[10];
    const float* mlpbn_b = (const float*)d_in[11];
    const float* mlp2_w = (const float*)d_in[12];
    const float* mlp2_b = (const float*)d_in[13];
    const float* bn_g   = (const float*)d_in[14];
    const float* bn_b   = (const float*)d_in[15];
    const float* bh1_w  = (const float*)d_in[16];
    const float* bh1_b  = (const float*)d_in[17];
    const float* bh2_w  = (const float*)d_in[18];
    const float* bh2_b  = (const float*)d_in[19];
    const float* bm_w   = (const float*)d_in[20];
    const float* bm_b   = (const float*)d_in[21];
    const float* ln_g   = (const float*)d_in[22];
    const float* ln_b   = (const float*)d_in[23];
    const float* clf1_w = (const float*)d_in[24];
    const float* clf1_b = (const float*)d_in[25];
    const float* clfbn_g = (const float*)d_in[26];
    const float* clfbn_b = (const float*)d_in[27];
    const float* clf2_w = (const float*)d_in[28];
    const float* clf2_b = (const float*)d_in[29];
    float* out = (float*)d_out;

    const int N = in_sizes[0] / 64;
    const int E = in_sizes[1] / 2;
    const int G = out_size / 10;

    float* ws = (float*)d_ws;
    float* h      = ws;                                  // N*128
    float* z      = h + (size_t)N * HH;                  // N*128
    float* t1     = z + (size_t)N * HH;                  // N*128
    float* assign = t1 + (size_t)N * HH;                 // N*8
    float* gmean  = assign + (size_t)N * 8;              // G*128
    float* num    = gmean + (size_t)G * HH;              // G*8*128
    float* den    = num + (size_t)G * 8 * HH;            // G*8
    float* blobs  = den + (size_t)G * 8;                 // G*8*128
    float* t4     = blobs + (size_t)G * 8 * HH;          // G*128
    float* stats  = t4 + (size_t)G * HH;                 // 256
    float* sc1    = stats + 256;
    float* sh1    = sc1 + 128;
    float* sc2    = sh1 + 128;
    float* sh2    = sc2 + 128;
    u16* Whi = (u16*)(sh2 + 128);                        // WTOT
    u16* Wlo = Whi + WTOT;                               // WTOT
    int* rowptr = (int*)(Wlo + WTOT);                    // N+1
    int* cursor = rowptr + (N + 1);                      // N (also deg)
    int* colidx = cursor + N;                            // E
    int* bsum   = colidx + E;                            // 256
    int* boff   = bsum + 256;                            // 256
    u16* hb = (u16*)t1;   // aliases t1 (disjoint lifetimes)

    const dim3 B256(256), B128(128), B1024(1024);
    const int ntiles = (N + 63) / 64;
    const int gg = ntiles < 256 ? ntiles : 256;
    const int nch = (N + 255) / 256;
    const float invN = 1.f / (float)N;
    const float invG = 1.f / (float)G;

    // weight prep + CSR build + single stats clear
    k_prep<<<7, B256, 0, stream>>>(inp_w, mlp1_w, mlp2_w, Whi, Wlo);
    hipMemsetAsync(cursor, 0, (size_t)N * sizeof(int), stream);
    hipMemsetAsync(stats, 0, 256 * sizeof(float), stream);
    k_hist<<<(E + 255) / 256, B256, 0, stream>>>(ei, cursor, E);
    k_bsum<<<nch, B256, 0, stream>>>(cursor, bsum, N);
    k_scan1<<<1, B256, 0, stream>>>(bsum, boff, rowptr + N, nch);
    k_scan2<<<nch, B256, 0, stream>>>(cursor, boff, rowptr, cursor, N);
    k_fill<<<(E + 255) / 256, B256, 0, stream>>>(ei, cursor, colidx, E);

    // h = x @ inp_w + inp_b  (f32 h + bf16 hb)
    k_mgemm<64, 0, false, true><<<gg, B256, 0, stream>>>(
        x, Whi, Wlo, inp_b, nullptr, nullptr, h, hb, nullptr, N, ntiles);

    for (int l = 0; l < 3; l++) {
        k_gather<<<(N + 3) / 4, B256, 0, stream>>>(hb, h, rowptr, colidx,
                                                   elin_w + l * HH, elin_b + l * HH, z, N);
        // t1 = z @ W1 + b1 (stats into zeroed buffer; bnfin clears after)
        k_mgemm<128, 0, true, false><<<gg, B256, 0, stream>>>(
            z, Whi + 8192 + (size_t)l * 16384, Wlo + 8192 + (size_t)l * 16384,
            mlp1_b + l * HH, nullptr, nullptr, t1, nullptr, stats, N, ntiles);
        k_bnfin<<<1, B128, 0, stream>>>(stats, mlpbn_g + l * HH, mlpbn_b + l * HH, sc1, sh1, invN);
        // t2 = relu(bn(t1)) @ W2 + b2 -> z
        k_mgemm<128, 1, true, false><<<gg, B256, 0, stream>>>(
            t1, Whi + 8192 + (size_t)(3 + l) * 16384, Wlo + 8192 + (size_t)(3 + l) * 16384,
            mlp2_b + l * HH, sc1, sh1, z, nullptr, stats, N, ntiles);
        k_bnfin<<<1, B128, 0, stream>>>(stats, bn_g + l * HH, bn_b + l * HH, sc2, sh2, invN);
        // h = relu(bn(z)) -> f32 h + bf16 hb
        k_bnrelu<<<(N * 32 + 255) / 256, B256, 0, stream>>>(z, sc2, sh2, h, hb, N * 32);
    }

    k_assign<<<(N + 31) / 32, B256, 0, stream>>>(h, gumbel, bh1_w, bh1_b, bh2_w, bh2_b, assign, N);
    k_pool<<<G, B1024, 0, stream>>>(h, assign, batch, gmean, num, den, N);
    k_blob<<<G * 8, B128, 0, stream>>>(num, den, bm_w, bm_b, ln_g, ln_b, blobs);
    k_clf1<<<G, B128, 0, stream>>>(gmean, blobs, clf1_w, clf1_b, t4, stats);
    k_bnfin<<<1, B128, 0, stream>>>(stats, clfbn_g, clfbn_b, sc1, sh1, invG);
    k_clf2<<<G, B128, 0, stream>>>(t4, sc1, sh1, clf2_w, clf2_b, out);
}

// Round 7
// 544.730 us; speedup vs baseline: 9.7833x; 1.1439x over previous
//
#include <hip/hip_runtime.h>
#include <hip/hip_bf16.h>

// ---------------------------------------------------------------------------
// SoftBlobGIN round 7: pre-split hi/lo activations (zero-VALU GEMM staging),
// 512-thread 128-row mgemm tiles (2 waves/SIMD), 2-wave-per-node gather with
// 4-edge unroll, per-block BN finalize (no bnfin launches).
// ---------------------------------------------------------------------------

#define HH 128
typedef unsigned short u16;
typedef unsigned int u32;
typedef __attribute__((ext_vector_type(8))) short bf16x8;
typedef __attribute__((ext_vector_type(4))) float f32x4;

__device__ __forceinline__ void atomAddF(float* p, float v) { unsafeAtomicAdd(p, v); }

__device__ __forceinline__ u16 f2bf(float f) {          // RNE f32->bf16
    u32 u = __float_as_uint(f);
    u += 0x7fffu + ((u >> 16) & 1u);
    return (u16)(u >> 16);
}
__device__ __forceinline__ float bf2f_lo(u32 u) { return __uint_as_float(u << 16); }
__device__ __forceinline__ float bf2f_hi(u32 u) { return __uint_as_float(u & 0xffff0000u); }
__device__ __forceinline__ void split2(float v, u16& hi, u16& lo) {
    u16 h_ = f2bf(v);
    float hf = __uint_as_float(((u32)h_) << 16);
    hi = h_;
    lo = f2bf(v - hf);
}
__device__ __forceinline__ u32 swz(u32 row, u32 kByte, u32 strideB) {
    return (row * strideB + kByte) ^ ((row & 7u) << 4);
}

#define WTOT (8192 + 6 * 16384)

// ---------------- weight prep ----------------
__global__ void k_prep(const float* __restrict__ inp_w, const float* __restrict__ m1,
                       const float* __restrict__ m2, u16* __restrict__ Whi,
                       u16* __restrict__ Wlo) {
    int b = blockIdx.x;  // 0..6
    int t = threadIdx.x; // 256
    if (b == 0) {
        for (int idx = t; idx < 128 * 64; idx += 256) {
            int c = idx >> 6, k = idx & 63;
            u16 hi, lo;
            split2(inp_w[k * 128 + c], hi, lo);
            Whi[idx] = hi; Wlo[idx] = lo;
        }
    } else {
        const float* W = (b <= 3) ? m1 + (size_t)(b - 1) * 16384
                                  : m2 + (size_t)(b - 4) * 16384;
        u16* dh = Whi + 8192 + (size_t)(b - 1) * 16384;
        u16* dl = Wlo + 8192 + (size_t)(b - 1) * 16384;
        for (int idx = t; idx < 16384; idx += 256) {
            int c = idx >> 7, k = idx & 127;
            u16 hi, lo;
            split2(W[k * 128 + c], hi, lo);
            dh[idx] = hi; dl[idx] = lo;
        }
    }
}

// ---------------- x pre-split ----------------
__global__ void k_split(const float* __restrict__ x, u16* __restrict__ xhi,
                        u16* __restrict__ xlo, int total4) {
    int i = blockIdx.x * 256 + threadIdx.x;
    if (i >= total4) return;
    float4 v = *(const float4*)(x + (size_t)i * 4);
    u16 h0, h1, h2, h3, l0, l1, l2, l3;
    split2(v.x, h0, l0); split2(v.y, h1, l1);
    split2(v.z, h2, l2); split2(v.w, h3, l3);
    uint2 ph = {(u32)h0 | ((u32)h1 << 16), (u32)h2 | ((u32)h3 << 16)};
    uint2 pl = {(u32)l0 | ((u32)l1 << 16), (u32)l2 | ((u32)l3 << 16)};
    *(uint2*)(xhi + (size_t)i * 4) = ph;
    *(uint2*)(xlo + (size_t)i * 4) = pl;
}

// ---------------- CSR build ----------------
__global__ void k_hist(const int* __restrict__ ei, int* __restrict__ deg, int E) {
    int e = blockIdx.x * 256 + threadIdx.x;
    if (e >= E) return;
    atomicAdd(&deg[ei[E + e]], 1);
}

__global__ void k_bsum(const int* __restrict__ deg, int* __restrict__ bsum, int N) {
    int t = threadIdx.x;
    int i = blockIdx.x * 256 + t;
    int v = (i < N) ? deg[i] : 0;
    for (int o = 32; o; o >>= 1) v += __shfl_down(v, o);
    __shared__ int ws_[4];
    if ((t & 63) == 0) ws_[t >> 6] = v;
    __syncthreads();
    if (t == 0) bsum[blockIdx.x] = ws_[0] + ws_[1] + ws_[2] + ws_[3];
}

__global__ void k_scan1(const int* __restrict__ bsum, int* __restrict__ boff,
                        int* __restrict__ rowptrN, int nch) {
    int t = threadIdx.x;  // 256
    int v = (t < nch) ? bsum[t] : 0;
    int l = t & 63, w = t >> 6;
    int sv = v;
    for (int o = 1; o < 64; o <<= 1) { int u = __shfl_up(sv, o); if (l >= o) sv += u; }
    __shared__ int wsum[4];
    if (l == 63) wsum[w] = sv;
    __syncthreads();
    int add = 0;
    for (int j = 0; j < w; j++) add += wsum[j];
    if (t < nch) boff[t] = sv - v + add;
    if (t == nch - 1) *rowptrN = sv + add;
}

__global__ void k_scan2(const int* __restrict__ deg, const int* __restrict__ boff,
                        int* __restrict__ rowptr, int* __restrict__ cursor, int N) {
    int b = blockIdx.x, t = threadIdx.x, i = b * 256 + t;
    int v = (i < N) ? deg[i] : 0;
    int l = t & 63, w = t >> 6;
    int sv = v;
    for (int o = 1; o < 64; o <<= 1) { int u = __shfl_up(sv, o); if (l >= o) sv += u; }
    __shared__ int wsum[4];
    if (l == 63) wsum[w] = sv;
    __syncthreads();
    int add = boff[b];
    for (int j = 0; j < w; j++) add += wsum[j];
    if (i < N) { int e = sv - v + add; rowptr[i] = e; cursor[i] = e; }
}

__global__ void k_fill(const int* __restrict__ ei, int* __restrict__ cursor,
                       int* __restrict__ col, int E) {
    int e = blockIdx.x * 256 + threadIdx.x;
    if (e >= E) return;
    int src = ei[e];
    int dst = ei[E + e];
    int pos = atomicAdd(&cursor[dst], 1);
    col[pos] = src;
}

// ---------------- persistent-B split-precision MFMA GEMM (512 thr, 128-row) -
// MODE 1: f32 input, bn-relu applied in staging (per-block finalize from
//         statsIn + gamma/beta). MODE 2: pre-split bf16 hi/lo input.
// STATS: column sum/sumsq of output -> atomics into statsOut[256]
// BOUT: also write bf16 copy of output
template <int KD, int MODE, bool STATS, bool BOUT>
__global__ __launch_bounds__(512) void k_mgemm(
    const float* __restrict__ inf, const u16* __restrict__ inhi,
    const u16* __restrict__ inlo, const u16* __restrict__ Whi,
    const u16* __restrict__ Wlo, const float* __restrict__ bias,
    const float* __restrict__ statsIn, const float* __restrict__ gamma,
    const float* __restrict__ beta, float invN,
    float* __restrict__ out, u16* __restrict__ outb,
    float* __restrict__ statsOut, int Nrows, int ntiles) {
    __shared__ u16 s_Ahi[128 * KD];
    __shared__ u16 s_Alo[128 * KD];
    __shared__ u16 s_Bhi[128 * KD];
    __shared__ u16 s_Blo[128 * KD];
    __shared__ float s_red[2][8][128];
    __shared__ float s_sc[128], s_sh[128];
    const int t = threadIdx.x;
    constexpr u32 STR = KD * 2;
    constexpr int KCB = KD / 8;              // uint4 chunks per row
    constexpr int KCF = KD / 4;              // float4 chunks per row
    constexpr int NAU = (128 * KCB) / 512;   // A uint4/thread (MODE 2)
    constexpr int NAF = (128 * KCF) / 512;   // A float4/thread (MODE 1)
    constexpr int NB  = (128 * KCB) / 512;   // B uint4/thread

    // ---- stage B once; MODE1: per-block BN finalize ----
#pragma unroll
    for (int i = 0; i < NB; i++) {
        int idx = i * 512 + t;
        int c = idx / KCB, kc = idx % KCB;
        u32 off = swz(c, kc * 16, STR);
        *(uint4*)((char*)s_Bhi + off) = *(const uint4*)(Whi + (size_t)c * KD + kc * 8);
        *(uint4*)((char*)s_Blo + off) = *(const uint4*)(Wlo + (size_t)c * KD + kc * 8);
    }
    if (MODE == 1 && t < 128) {
        float m = statsIn[t] * invN;
        float var = statsIn[128 + t] * invN - m * m;
        float s = gamma[t] * rsqrtf(var + 1e-5f);
        s_sc[t] = s;
        s_sh[t] = beta[t] - m * s;
    }
    __syncthreads();

    // ---- prologue prefetch of first tile ----
    float4 rf[MODE == 1 ? NAF : 1];
    uint4 rh[MODE == 2 ? NAU : 1], rl[MODE == 2 ? NAU : 1];
    int tile = blockIdx.x;
    if (tile < ntiles) {
        if (MODE == 1) {
#pragma unroll
            for (int i = 0; i < NAF; i++) {
                int idx = i * 512 + t;
                int r = idx / KCF, kc = idx % KCF;
                int gr = tile * 128 + r;
                rf[i] = (gr < Nrows) ? *(const float4*)(inf + (size_t)gr * KD + kc * 4)
                                     : (float4){0.f, 0.f, 0.f, 0.f};
            }
        } else {
#pragma unroll
            for (int i = 0; i < NAU; i++) {
                int idx = i * 512 + t;
                int r = idx / KCB, kc = idx % KCB;
                int gr = tile * 128 + r;
                if (gr < Nrows) {
                    rh[i] = *(const uint4*)(inhi + (size_t)gr * KD + kc * 8);
                    rl[i] = *(const uint4*)(inlo + (size_t)gr * KD + kc * 8);
                } else {
                    rh[i] = (uint4){0, 0, 0, 0};
                    rl[i] = (uint4){0, 0, 0, 0};
                }
            }
        }
    }

    const int l = t & 63, w = t >> 6;        // 8 waves
    const int c0 = l & 15;
    const u32 kOffB = (u32)(l >> 4) * 16u;
    const u32 rA_row = w * 16 + c0;

    for (; tile < ntiles; tile += gridDim.x) {
        // ---- stage A from regs ----
        if (MODE == 1) {
#pragma unroll
            for (int i = 0; i < NAF; i++) {
                int idx = i * 512 + t;
                int r = idx / KCF, kc = idx % KCF;
                float4 v = rf[i];
                int k0 = kc * 4;
                v.x = fmaxf(v.x * s_sc[k0 + 0] + s_sh[k0 + 0], 0.f);
                v.y = fmaxf(v.y * s_sc[k0 + 1] + s_sh[k0 + 1], 0.f);
                v.z = fmaxf(v.z * s_sc[k0 + 2] + s_sh[k0 + 2], 0.f);
                v.w = fmaxf(v.w * s_sc[k0 + 3] + s_sh[k0 + 3], 0.f);
                u16 h0, h1, h2, h3, l0, l1, l2, l3;
                split2(v.x, h0, l0); split2(v.y, h1, l1);
                split2(v.z, h2, l2); split2(v.w, h3, l3);
                uint2 ph = {(u32)h0 | ((u32)h1 << 16), (u32)h2 | ((u32)h3 << 16)};
                uint2 pl = {(u32)l0 | ((u32)l1 << 16), (u32)l2 | ((u32)l3 << 16)};
                u32 off = swz(r, kc * 8, STR);
                *(uint2*)((char*)s_Ahi + off) = ph;
                *(uint2*)((char*)s_Alo + off) = pl;
            }
        } else {
#pragma unroll
            for (int i = 0; i < NAU; i++) {
                int idx = i * 512 + t;
                int r = idx / KCB, kc = idx % KCB;
                u32 off = swz(r, kc * 16, STR);
                *(uint4*)((char*)s_Ahi + off) = rh[i];
                *(uint4*)((char*)s_Alo + off) = rl[i];
            }
        }
        __syncthreads();

        // ---- prefetch next tile ----
        int nxt = tile + gridDim.x;
        if (nxt < ntiles) {
            if (MODE == 1) {
#pragma unroll
                for (int i = 0; i < NAF; i++) {
                    int idx = i * 512 + t;
                    int r = idx / KCF, kc = idx % KCF;
                    int gr = nxt * 128 + r;
                    rf[i] = (gr < Nrows) ? *(const float4*)(inf + (size_t)gr * KD + kc * 4)
                                         : (float4){0.f, 0.f, 0.f, 0.f};
                }
            } else {
#pragma unroll
                for (int i = 0; i < NAU; i++) {
                    int idx = i * 512 + t;
                    int r = idx / KCB, kc = idx % KCB;
                    int gr = nxt * 128 + r;
                    if (gr < Nrows) {
                        rh[i] = *(const uint4*)(inhi + (size_t)gr * KD + kc * 8);
                        rl[i] = *(const uint4*)(inlo + (size_t)gr * KD + kc * 8);
                    } else {
                        rh[i] = (uint4){0, 0, 0, 0};
                        rl[i] = (uint4){0, 0, 0, 0};
                    }
                }
            }
        }

        // ---- MFMA (3 per sub-tile: hi*hi + lo*hi + hi*lo) ----
        f32x4 acc[8];
#pragma unroll
        for (int n = 0; n < 8; n++) acc[n] = (f32x4){0.f, 0.f, 0.f, 0.f};
#pragma unroll
        for (int kk = 0; kk < KD / 32; kk++) {
            u32 kb = kk * 64 + kOffB;
            bf16x8 ah = *(const bf16x8*)((char*)s_Ahi + swz(rA_row, kb, STR));
            bf16x8 al = *(const bf16x8*)((char*)s_Alo + swz(rA_row, kb, STR));
#pragma unroll
            for (int n = 0; n < 8; n++) {
                u32 ob = swz(n * 16 + c0, kb, STR);
                bf16x8 bh = *(const bf16x8*)((char*)s_Bhi + ob);
                bf16x8 bl = *(const bf16x8*)((char*)s_Blo + ob);
                acc[n] = __builtin_amdgcn_mfma_f32_16x16x32_bf16(ah, bh, acc[n], 0, 0, 0);
                acc[n] = __builtin_amdgcn_mfma_f32_16x16x32_bf16(al, bh, acc[n], 0, 0, 0);
                acc[n] = __builtin_amdgcn_mfma_f32_16x16x32_bf16(ah, bl, acc[n], 0, 0, 0);
            }
        }

        // ---- epilogue ----
        const int rbase = tile * 128 + w * 16 + ((l >> 4) << 2);
#pragma unroll
        for (int n = 0; n < 8; n++) {
            const int colc = n * 16 + c0;
            const float bv = bias[colc];
            float s = 0.f, q = 0.f;
#pragma unroll
            for (int j = 0; j < 4; j++) {
                int gr = rbase + j;
                if (gr < Nrows) {
                    float v = acc[n][j] + bv;
                    out[(size_t)gr * HH + colc] = v;
                    if (BOUT) outb[(size_t)gr * HH + colc] = f2bf(v);
                    s += v;
                    q += v * v;
                }
            }
            if (STATS) {
                s += __shfl_xor(s, 16); s += __shfl_xor(s, 32);
                q += __shfl_xor(q, 16); q += __shfl_xor(q, 32);
                if (l < 16) {
                    s_red[0][w][n * 16 + l] = s;
                    s_red[1][w][n * 16 + l] = q;
                }
            }
        }
        __syncthreads();
        if (STATS && t < 128) {
            float S = 0.f, Q = 0.f;
#pragma unroll
            for (int ww = 0; ww < 8; ww++) { S += s_red[0][ww][t]; Q += s_red[1][ww][t]; }
            atomAddF(&statsOut[t], S);
            atomAddF(&statsOut[HH + t], Q);
        }
    }
}

// ---------------- gather: 2 waves/node, 4-edge unroll, writes zhi/zlo -------
__global__ __launch_bounds__(256) void k_gather(
    const u16* __restrict__ hb, const float* __restrict__ h,
    const int* __restrict__ rowptr, const int* __restrict__ col,
    const float* __restrict__ ew, const float* __restrict__ eb,
    u16* __restrict__ zhi, u16* __restrict__ zlo, int N) {
    __shared__ float2 s_part[2][64];
    const int wv = threadIdx.x >> 6;
    const int lane = threadIdx.x & 63;
    const int node = blockIdx.x * 2 + (wv >> 1);
    const int hf = wv & 1;
    const int c2 = lane * 2;
    float2 acc = {0.f, 0.f};
    const bool valid = node < N;
    float2 ee = {0.f, 0.f};
    if (valid) {
        ee.x = ew[c2] + eb[c2];
        ee.y = ew[c2 + 1] + eb[c2 + 1];
        const int s = rowptr[node], eend = rowptr[node + 1];
        int e = s + hf;
        for (; e + 6 < eend; e += 8) {
            int s0 = col[e], s1 = col[e + 2], s2 = col[e + 4], s3 = col[e + 6];
            u32 u0 = *(const u32*)(hb + (size_t)s0 * HH + c2);
            u32 u1 = *(const u32*)(hb + (size_t)s1 * HH + c2);
            u32 u2 = *(const u32*)(hb + (size_t)s2 * HH + c2);
            u32 u3 = *(const u32*)(hb + (size_t)s3 * HH + c2);
            acc.x += fmaxf(bf2f_lo(u0) + ee.x, 0.f) + fmaxf(bf2f_lo(u1) + ee.x, 0.f) +
                     fmaxf(bf2f_lo(u2) + ee.x, 0.f) + fmaxf(bf2f_lo(u3) + ee.x, 0.f);
            acc.y += fmaxf(bf2f_hi(u0) + ee.y, 0.f) + fmaxf(bf2f_hi(u1) + ee.y, 0.f) +
                     fmaxf(bf2f_hi(u2) + ee.y, 0.f) + fmaxf(bf2f_hi(u3) + ee.y, 0.f);
        }
        for (; e < eend; e += 2) {
            u32 u0 = *(const u32*)(hb + (size_t)col[e] * HH + c2);
            acc.x += fmaxf(bf2f_lo(u0) + ee.x, 0.f);
            acc.y += fmaxf(bf2f_hi(u0) + ee.y, 0.f);
        }
    }
    if (hf) s_part[wv >> 1][lane] = acc;
    __syncthreads();
    if (!hf && valid) {
        float2 p = s_part[wv >> 1][lane];
        const float2 hn = *(const float2*)(h + (size_t)node * HH + c2);
        float zx = hn.x + acc.x + p.x;
        float zy = hn.y + acc.y + p.y;
        u16 h0, h1, l0, l1;
        split2(zx, h0, l0);
        split2(zy, h1, l1);
        *(u32*)(zhi + (size_t)node * HH + c2) = (u32)h0 | ((u32)h1 << 16);
        *(u32*)(zlo + (size_t)node * HH + c2) = (u32)l0 | ((u32)l1 << 16);
    }
}

// ---------------- bnrelu: per-block BN finalize; f32 h + bf16 hb ------------
__global__ void k_bnrelu(const float* __restrict__ t, const float* __restrict__ stats,
                         const float* __restrict__ g, const float* __restrict__ b,
                         float invN, float* __restrict__ h, u16* __restrict__ hb,
                         int total4) {
    int i = blockIdx.x * 256 + threadIdx.x;
    if (i >= total4) return;
    int c4 = (i & 31) << 2;
    float sc[4], sh[4];
#pragma unroll
    for (int j = 0; j < 4; j++) {
        float m = stats[c4 + j] * invN;
        float var = stats[128 + c4 + j] * invN - m * m;
        float s = g[c4 + j] * rsqrtf(var + 1e-5f);
        sc[j] = s;
        sh[j] = b[c4 + j] - m * s;
    }
    float4 v = *(const float4*)(t + (size_t)i * 4);
    float4 o;
    o.x = fmaxf(v.x * sc[0] + sh[0], 0.f);
    o.y = fmaxf(v.y * sc[1] + sh[1], 0.f);
    o.z = fmaxf(v.z * sc[2] + sh[2], 0.f);
    o.w = fmaxf(v.w * sc[3] + sh[3], 0.f);
    *(float4*)(h + (size_t)i * 4) = o;
    uint2 p = {(u32)f2bf(o.x) | ((u32)f2bf(o.y) << 16),
               (u32)f2bf(o.z) | ((u32)f2bf(o.w) << 16)};
    *(uint2*)(hb + (size_t)i * 4) = p;
}

// ---------------- assign ----------------
__global__ __launch_bounds__(256) void k_assign(
    const float* __restrict__ h, const float* __restrict__ gum,
    const float* __restrict__ w1, const float* __restrict__ b1,
    const float* __restrict__ w2, const float* __restrict__ b2,
    float* __restrict__ assign, int N) {
    __shared__ float s_w1[128 * 64];
    __shared__ float s_w2[64 * 8];
    __shared__ float s_h[32][128];
    __shared__ float s_hid[32][64];
    const int t = threadIdx.x;
    const int n0 = blockIdx.x * 32;
    for (int i = t; i < 128 * 64; i += 256) s_w1[i] = w1[i];
    for (int i = t; i < 512; i += 256) s_w2[i] = w2[i];
    for (int i = t; i < 32 * 32; i += 256) {
        int r = i >> 5, c4 = (i & 31) << 2;
        int gn = n0 + r;
        float4 v = {0.f, 0.f, 0.f, 0.f};
        if (gn < N) v = *(const float4*)(h + (size_t)gn * HH + c4);
        *(float4*)(&s_h[r][c4]) = v;
    }
    __syncthreads();
    for (int o = t; o < 32 * 64; o += 256) {
        int nn = o >> 6, j = o & 63;
        float acc = b1[j];
        for (int k = 0; k < 128; k++) acc = fmaf(s_h[nn][k], s_w1[k * 64 + j], acc);
        s_hid[nn][j] = fmaxf(acc, 0.f);
    }
    __syncthreads();
    int nn = t >> 3, kk = t & 7;
    int gn = n0 + nn;
    float a = b2[kk];
    for (int j = 0; j < 64; j++) a = fmaf(s_hid[nn][j], s_w2[j * 8 + kk], a);
    if (gn < N) a += gum[(size_t)gn * 8 + kk];
    float m = a;
    m = fmaxf(m, __shfl_xor(m, 1));
    m = fmaxf(m, __shfl_xor(m, 2));
    m = fmaxf(m, __shfl_xor(m, 4));
    float e = expf(a - m);
    float s = e;
    s += __shfl_xor(s, 1); s += __shfl_xor(s, 2); s += __shfl_xor(s, 4);
    if (gn < N) assign[(size_t)gn * 8 + kk] = e / s;
}

// ---------------- tail ----------------
__device__ __forceinline__ int lowerb(const int* __restrict__ arr, int n, int val) {
    int lo = 0, hi = n;
    while (lo < hi) {
        int mid = (lo + hi) >> 1;
        if (arr[mid] < val) lo = mid + 1;
        else hi = mid;
    }
    return lo;
}

__global__ __launch_bounds__(1024) void k_pool(
    const float* __restrict__ h, const float* __restrict__ assign,
    const int* __restrict__ batch, float* __restrict__ gmean,
    float* __restrict__ num, float* __restrict__ den, int N) {
    __shared__ float4 s_num[4][8][32];
    __shared__ float4 s_gm[4][32];
    __shared__ float s_den[4][8];
    const int g = blockIdx.x;
    const int t = threadIdx.x;
    const int ns = t >> 8;
    const int k = (t >> 5) & 7;
    const int lane = t & 31;
    const int c4 = lane << 2;
    const int start = lowerb(batch, N, g);
    const int end = lowerb(batch, N, g + 1);
    float4 an = {0.f, 0.f, 0.f, 0.f};
    float4 gm = {0.f, 0.f, 0.f, 0.f};
    float ad = 0.f;
    for (int n = start + ns; n < end; n += 4) {
        float a = assign[(size_t)n * 8 + k];
        const float4 hv = *(const float4*)(h + (size_t)n * HH + c4);
        an.x = fmaf(a, hv.x, an.x);
        an.y = fmaf(a, hv.y, an.y);
        an.z = fmaf(a, hv.z, an.z);
        an.w = fmaf(a, hv.w, an.w);
        if (k == 0) { gm.x += hv.x; gm.y += hv.y; gm.z += hv.z; gm.w += hv.w; }
        ad += a;
    }
    s_num[ns][k][lane] = an;
    if (k == 0) s_gm[ns][lane] = gm;
    if (lane == 0) s_den[ns][k] = ad;
    __syncthreads();
    if (t < 256) {
        float4 a0 = s_num[0][k][lane], a1 = s_num[1][k][lane];
        float4 a2 = s_num[2][k][lane], a3 = s_num[3][k][lane];
        float4 o = {a0.x + a1.x + a2.x + a3.x, a0.y + a1.y + a2.y + a3.y,
                    a0.z + a1.z + a2.z + a3.z, a0.w + a1.w + a2.w + a3.w};
        *(float4*)(num + ((size_t)g * 8 + k) * HH + c4) = o;
        if (t < 32) {
            float4 g0 = s_gm[0][lane], g1 = s_gm[1][lane];
            float4 g2 = s_gm[2][lane], g3 = s_gm[3][lane];
            int cnt = end - start;
            float inv = 1.f / (float)(cnt > 0 ? cnt : 1);
            float4 om = {(g0.x + g1.x + g2.x + g3.x) * inv,
                         (g0.y + g1.y + g2.y + g3.y) * inv,
                         (g0.z + g1.z + g2.z + g3.z) * inv,
                         (g0.w + g1.w + g2.w + g3.w) * inv};
            *(float4*)(gmean + (size_t)g * HH + c4) = om;
        }
        if (t < 8) den[(size_t)g * 8 + t] =
            s_den[0][t] + s_den[1][t] + s_den[2][t] + s_den[3][t];
    }
}

__global__ void k_blob(const float* __restrict__ num, const float* __restrict__ den,
                       const float* __restrict__ w, const float* __restrict__ b,
                       const float* __restrict__ lg, const float* __restrict__ lb,
                       float* __restrict__ blobs) {
    const int gk = blockIdx.x;
    const int c = threadIdx.x;  // 128
    __shared__ float srow[128];
    __shared__ float red[4];
    float d = den[gk] + 1e-8f;
    srow[c] = num[(size_t)gk * HH + c] / d;
    __syncthreads();
    float acc = b[c];
    for (int j = 0; j < 128; j++) acc = fmaf(srow[j], w[j * HH + c], acc);
    float y = fmaxf(acc, 0.f);
    float s = y, q = y * y;
    for (int off = 32; off > 0; off >>= 1) {
        s += __shfl_down(s, off);
        q += __shfl_down(q, off);
    }
    if ((c & 63) == 0) { red[(c >> 6) * 2] = s; red[(c >> 6) * 2 + 1] = q; }
    __syncthreads();
    float S = red[0] + red[2], Q = red[1] + red[3];
    float m = S * (1.f / 128.f);
    float var = Q * (1.f / 128.f) - m * m;
    blobs[(size_t)gk * HH + c] = (y - m) * rsqrtf(var + 1e-5f) * lg[c] + lb[c];
}

__global__ void k_clf1(const float* __restrict__ gmean, const float* __restrict__ blobs,
                       const float* __restrict__ w, const float* __restrict__ bias,
                       float* __restrict__ t4, float* __restrict__ stats) {
    int g = blockIdx.x;
    int c = threadIdx.x;  // 128
    __shared__ float s[256];
    float m = blobs[((size_t)g * 8) * HH + c];
#pragma unroll
    for (int k = 1; k < 8; k++) m = fmaxf(m, blobs[((size_t)g * 8 + k) * HH + c]);
    s[c] = gmean[(size_t)g * HH + c];
    s[128 + c] = m;
    __syncthreads();
    float acc = bias[c];
    for (int j = 0; j < 256; j++) acc = fmaf(s[j], w[j * HH + c], acc);
    t4[(size_t)g * HH + c] = acc;
    atomAddF(&stats[c], acc);
    atomAddF(&stats[HH + c], acc * acc);
}

__global__ void k_clf2(const float* __restrict__ t4, const float* __restrict__ stats,
                       const float* __restrict__ g_, const float* __restrict__ b_,
                       float invG, const float* __restrict__ w,
                       const float* __restrict__ bias, float* __restrict__ out) {
    int g = blockIdx.x;
    int t = threadIdx.x;  // 128
    __shared__ float s[128];
    float m = stats[t] * invG;
    float var = stats[128 + t] * invG - m * m;
    float sc = g_[t] * rsqrtf(var + 1e-5f);
    float sh = b_[t] - m * sc;
    s[t] = fmaxf(t4[(size_t)g * HH + t] * sc + sh, 0.f);
    __syncthreads();
    if (t < 10) {
        float acc = bias[t];
        for (int j = 0; j < 128; j++) acc = fmaf(s[j], w[j * 10 + t], acc);
        out[(size_t)g * 10 + t] = acc;
    }
}

extern "C" void kernel_launch(void* const* d_in, const int* in_sizes, int n_in,
                              void* d_out, int out_size, void* d_ws, size_t ws_size,
                              hipStream_t stream) {
    const float* x      = (const float*)d_in[0];
    const int*   ei     = (const int*)d_in[1];
    const int*   batch  = (const int*)d_in[2];
    const float* gumbel = (const float*)d_in[3];
    const float* inp_w  = (const float*)d_in[4];
    const float* inp_b  = (const float*)d_in[5];
    const float* elin_w = (const float*)d_in[6];
    const float* elin_b = (const float*)d_in[7];
    const float* mlp1_w = (const float*)d_in[8];
    const float* mlp1_b = (const float*)d_in[9];
    const float* mlpbn_g = (const float*)d_in[10];
    const float* mlpbn_b = (const float*)d_in[11];
    const float* mlp2_w = (const float*)d_in[12];
    const float* mlp2_b = (const float*)d_in[13];
    const float* bn_g   = (const float*)d_in[14];
    const float* bn_b   = (const float*)d_in[15];
    const float* bh1_w  = (const float*)d_in[16];
    const float* bh1_b  = (const float*)d_in[17];
    const float* bh2_w  = (const float*)d_in[18];
    const float* bh2_b  = (const float*)d_in[19];
    const float* bm_w   = (const float*)d_in[20];
    const float* bm_b   = (const float*)d_in[21];
    const float* ln_g   = (const float*)d_in[22];
    const float* ln_b   = (const float*)d_in[23];
    const float* clf1_w = (const float*)d_in[24];
    const float* clf1_b = (const float*)d_in[25];
    const float* clfbn_g = (const float*)d_in[26];
    const float* clfbn_b = (const float*)d_in[27];
    const float* clf2_w = (const float*)d_in[28];
    const float* clf2_b = (const float*)d_in[29];
    float* out = (float*)d_out;

    const int N = in_sizes[0] / 64;
    const int E = in_sizes[1] / 2;
    const int G = out_size / 10;

    float* ws = (float*)d_ws;
    float* h      = ws;                                  // N*128
    float* zbuf   = h + (size_t)N * HH;                  // N*128 f32 (multi-use)
    float* t1     = zbuf + (size_t)N * HH;               // N*128
    float* assign = t1 + (size_t)N * HH;                 // N*8
    float* gmean  = assign + (size_t)N * 8;              // G*128
    float* num    = gmean + (size_t)G * HH;              // G*8*128
    float* den    = num + (size_t)G * 8 * HH;            // G*8
    float* blobs  = den + (size_t)G * 8;                 // G*8*128
    float* t4     = blobs + (size_t)G * 8 * HH;          // G*128
    float* statsA = t4 + (size_t)G * HH;                 // 7*256 stats buffers
    u16* Whi = (u16*)(statsA + 7 * 256);                 // WTOT
    u16* Wlo = Whi + WTOT;                               // WTOT
    int* rowptr = (int*)(Wlo + WTOT);                    // N+1
    int* cursor = rowptr + (N + 1);                      // N (also deg)
    int* colidx = cursor + N;                            // E
    int* bsum   = colidx + E;                            // 256
    int* boff   = bsum + 256;                            // 256
    // aliases (disjoint lifetimes):
    u16* hb  = (u16*)t1;          // bf16 h copy; dead once mgemm1 writes t1
    u16* xhi = (u16*)zbuf;        // x pre-split, dead after input gemm
    u16* xlo = xhi + (size_t)N * 64;
    u16* zhi = (u16*)zbuf;        // gather output, dead after mgemm1
    u16* zlo = zhi + (size_t)N * HH;
    float* t2 = zbuf;             // mgemm2 output, dead after bnrelu

    const dim3 B256(256), B128(128), B512(512), B1024(1024);
    const int ntiles = (N + 127) / 128;
    const int gg = ntiles < 256 ? ntiles : 256;
    const int nch = (N + 255) / 256;
    const float invN = 1.f / (float)N;
    const float invG = 1.f / (float)G;

    // weight prep + CSR build + stats clear
    k_prep<<<7, B256, 0, stream>>>(inp_w, mlp1_w, mlp2_w, Whi, Wlo);
    hipMemsetAsync(cursor, 0, (size_t)N * sizeof(int), stream);
    hipMemsetAsync(statsA, 0, 7 * 256 * sizeof(float), stream);
    k_hist<<<(E + 255) / 256, B256, 0, stream>>>(ei, cursor, E);
    k_bsum<<<nch, B256, 0, stream>>>(cursor, bsum, N);
    k_scan1<<<1, B256, 0, stream>>>(bsum, boff, rowptr + N, nch);
    k_scan2<<<nch, B256, 0, stream>>>(cursor, boff, rowptr, cursor, N);
    k_fill<<<(E + 255) / 256, B256, 0, stream>>>(ei, cursor, colidx, E);
    k_split<<<(N * 16 + 255) / 256, B256, 0, stream>>>(x, xhi, xlo, N * 16);

    // h = x @ inp_w + inp_b  (f32 h + bf16 hb)
    k_mgemm<64, 2, false, true><<<gg, B512, 0, stream>>>(
        nullptr, xhi, xlo, Whi, Wlo, inp_b, nullptr, nullptr, nullptr, 0.f,
        h, hb, nullptr, N, ntiles);

    for (int l = 0; l < 3; l++) {
        float* sa = statsA + (size_t)(2 * l) * 256;
        float* sb = statsA + (size_t)(2 * l + 1) * 256;
        k_gather<<<(N + 1) / 2, B256, 0, stream>>>(hb, h, rowptr, colidx,
                                                   elin_w + l * HH, elin_b + l * HH,
                                                   zhi, zlo, N);
        // t1 = z @ W1 + b1 (stats -> sa)
        k_mgemm<128, 2, true, false><<<gg, B512, 0, stream>>>(
            nullptr, zhi, zlo, Whi + 8192 + (size_t)l * 16384,
            Wlo + 8192 + (size_t)l * 16384, mlp1_b + l * HH,
            nullptr, nullptr, nullptr, 0.f, t1, nullptr, sa, N, ntiles);
        // t2 = relu(bn(t1)) @ W2 + b2 (per-block finalize from sa; stats -> sb)
        k_mgemm<128, 1, true, false><<<gg, B512, 0, stream>>>(
            t1, nullptr, nullptr, Whi + 8192 + (size_t)(3 + l) * 16384,
            Wlo + 8192 + (size_t)(3 + l) * 16384, mlp2_b + l * HH,
            sa, mlpbn_g + l * HH, mlpbn_b + l * HH, invN, t2, nullptr, sb, N, ntiles);
        // h = relu(bn(t2)) (per-block finalize from sb) -> f32 h + bf16 hb
        k_bnrelu<<<(N * 32 + 255) / 256, B256, 0, stream>>>(
            t2, sb, bn_g + l * HH, bn_b + l * HH, invN, h, hb, N * 32);
    }

    k_assign<<<(N + 31) / 32, B256, 0, stream>>>(h, gumbel, bh1_w, bh1_b, bh2_w, bh2_b, assign, N);
    k_pool<<<G, B1024, 0, stream>>>(h, assign, batch, gmean, num, den, N);
    k_blob<<<G * 8, B128, 0, stream>>>(num, den, bm_w, bm_b, ln_g, ln_b, blobs);
    float* sc_ = statsA + 6 * 256;
    k_clf1<<<G, B128, 0, stream>>>(gmean, blobs, clf1_w, clf1_b, t4, sc_);
    k_clf2<<<G, B128, 0, stream>>>(t4, sc_, clfbn_g, clfbn_b, invG, clf2_w, clf2_b, out);
}